// Round 1
// baseline (2433.981 us; speedup 1.0000x reference)
//
#include <hip/hip_runtime.h>
#include <math.h>

#define DIM 64
#define NG 64
#define CIN 192
#define HID 128
#define NCONV 3
#define TB 8192
#define CUTOFF 12.0f
#define EPS 1e-5f

__device__ __forceinline__ float softplusf_(float y) {
    return (y > 0.f) ? y + log1pf(expf(-y)) : log1pf(expf(y));
}

// node[n][d] = embed_table[atom_types[n]][d]
__global__ void k_embed(const int* __restrict__ at, const float* __restrict__ emb,
                        float* __restrict__ node, int N) {
    int idx = blockIdx.x * blockDim.x + threadIdx.x;
    if (idx < N * DIM) {
        int n = idx >> 6, d = idx & 63;
        node[idx] = emb[at[n] * DIM + d];
    }
}

// T[l][i][d] = sum_g exp(coeff*(x_i-mu_g)^2) * W1[l][128+g][d]
__global__ void k_tables(const float* __restrict__ W1, float* __restrict__ T) {
    int row = blockIdx.x;            // 0 .. 3*TB-1
    int l = row / TB, i = row % TB;
    int d = threadIdx.x;             // 64 threads
    const float stepmu = CUTOFF / (float)(NG - 1);
    const float coeff = -0.5f / (stepmu * stepmu);
    float x = (float)i * (CUTOFF / (float)(TB - 1));
    __shared__ float rbf[NG];
    float mu = (float)d * stepmu;
    float diff = x - mu;
    rbf[d] = expf(coeff * diff * diff);
    __syncthreads();
    const float* w = W1 + (size_t)(l * CIN + 2 * DIM) * DIM;
    float acc = 0.f;
#pragma unroll 8
    for (int g = 0; g < NG; ++g) acc += rbf[g] * w[g * DIM + d];
    T[(size_t)row * DIM + d] = acc;
}

// P = node @ W1[l][0:64], Q = node @ W1[l][64:128]
__global__ void k_nodepq(const float* __restrict__ node, const float* __restrict__ W1, int l,
                         float* __restrict__ P, float* __restrict__ Q, int N) {
    __shared__ float wa[DIM * DIM];
    __shared__ float wb[DIM * DIM];
    const float* WA = W1 + (size_t)(l * CIN) * DIM;
    for (int k = threadIdx.x; k < DIM * DIM; k += blockDim.x) {
        wa[k] = WA[k];
        wb[k] = WA[DIM * DIM + k];
    }
    __syncthreads();
    int lane = threadIdx.x & 63, w = threadIdx.x >> 6;
    int wpb = blockDim.x >> 6;
    for (int n = blockIdx.x * wpb + w; n < N; n += gridDim.x * wpb) {
        float nv = node[(size_t)n * DIM + lane];
        float ap = 0.f, aq = 0.f;
#pragma unroll 8
        for (int k = 0; k < DIM; ++k) {
            float b = __shfl(nv, k);
            ap += b * wa[k * DIM + lane];
            aq += b * wb[k * DIM + lane];
        }
        P[(size_t)n * DIM + lane] = ap;
        Q[(size_t)n * DIM + lane] = aq;
    }
}

// PHASE 1: stats over z1.  PHASE 2: stats over f=sigmoid(bn1(z1)).
// PHASE 3: h = f * softplus(bn2(f)), scatter-add into agg[dst].
template <int PHASE>
__global__ void k_edge(const int* __restrict__ src, const int* __restrict__ dst,
                       const float* __restrict__ dist,
                       const float* __restrict__ P, const float* __restrict__ Q,
                       const float* __restrict__ T, const float* __restrict__ b1,
                       const float* __restrict__ coef1, const float* __restrict__ coef2,
                       double* __restrict__ stats, float* __restrict__ agg, int E) {
    int lane = threadIdx.x & 63;
    int w = threadIdx.x >> 6;
    int wpb = blockDim.x >> 6;
    int gw = blockIdx.x * wpb + w, nw = gridDim.x * wpb;
    float bv = b1[lane];
    float a1 = 0.f, c1 = 0.f, a2 = 0.f, c2 = 0.f;
    if (PHASE >= 2) { a1 = coef1[lane]; c1 = coef1[64 + lane]; }
    if (PHASE == 3) { a2 = coef2[lane]; c2 = coef2[64 + lane]; }
    const float inv_step = (float)(TB - 1) / CUTOFF;
    float s0 = 0.f, s1 = 0.f;
    int nchunks = (E + 63) >> 6;
    for (int ch = gw; ch < nchunks; ch += nw) {
        int base = ch << 6;
        int e = base + lane;
        int sv = 0, tv = 0;
        float xv = 0.f;
        if (e < E) { sv = src[e]; tv = dst[e]; xv = dist[e]; }
        int cnt = min(64, E - base);
        for (int j = 0; j < cnt; ++j) {
            int s = __shfl(sv, j), t = __shfl(tv, j);
            float x = __shfl(xv, j);
            float u = x * inv_step;
            int i = (int)u;
            i = max(0, min(i, TB - 2));
            float fr = u - (float)i;
            float t0 = T[(size_t)i * DIM + lane];
            float t1 = T[(size_t)(i + 1) * DIM + lane];
            float z = P[(size_t)s * DIM + lane] + Q[(size_t)t * DIM + lane]
                    + t0 + fr * (t1 - t0) + bv;
            if (PHASE == 1) {
                s0 += z; s1 += z * z;
            } else {
                float f = 1.f / (1.f + expf(-(a1 * z + c1)));
                if (PHASE == 2) {
                    s0 += f; s1 += f * f;
                } else {
                    float h = f * softplusf_(a2 * f + c2);
                    unsafeAtomicAdd(&agg[(size_t)t * DIM + lane], h);
                }
            }
        }
    }
    if (PHASE <= 2) {
        __shared__ float red0[4][64];
        __shared__ float red1[4][64];
        red0[w][lane] = s0;
        red1[w][lane] = s1;
        __syncthreads();
        if (threadIdx.x < 64) {
            float t0 = 0.f, t1 = 0.f;
            for (int q = 0; q < wpb; ++q) { t0 += red0[q][threadIdx.x]; t1 += red1[q][threadIdx.x]; }
            atomicAdd(&stats[threadIdx.x], (double)t0);
            atomicAdd(&stats[64 + threadIdx.x], (double)t1);
        }
    }
}

// m=sum/cnt, v=sq/cnt-m^2; a=g/sqrt(v+eps), c=bt-a*m
__global__ void k_finalize(const double* __restrict__ stats, const float* __restrict__ g,
                           const float* __restrict__ bt, double invcnt, float* __restrict__ coef) {
    int d = threadIdx.x;  // 64 threads
    double m = stats[d] * invcnt;
    double v = stats[64 + d] * invcnt - m * m;
    float a = g[d] / sqrtf((float)v + EPS);
    coef[d] = a;
    coef[64 + d] = bt[d] - a * (float)m;
}

__global__ void k_nodestats(const float* __restrict__ agg, double* __restrict__ stats, int N) {
    int lane = threadIdx.x & 63, w = threadIdx.x >> 6;
    int wpb = blockDim.x >> 6;
    float s0 = 0.f, s1 = 0.f;
    for (int n = blockIdx.x * wpb + w; n < N; n += gridDim.x * wpb) {
        float v = agg[(size_t)n * DIM + lane];
        s0 += v; s1 += v * v;
    }
    __shared__ float red0[4][64];
    __shared__ float red1[4][64];
    red0[w][lane] = s0;
    red1[w][lane] = s1;
    __syncthreads();
    if (threadIdx.x < 64) {
        float t0 = 0.f, t1 = 0.f;
        for (int q = 0; q < wpb; ++q) { t0 += red0[q][threadIdx.x]; t1 += red1[q][threadIdx.x]; }
        atomicAdd(&stats[threadIdx.x], (double)t0);
        atomicAdd(&stats[64 + threadIdx.x], (double)t1);
    }
}

__global__ void k_nodeupd(float* __restrict__ node, const float* __restrict__ agg,
                          const float* __restrict__ coef, int N) {
    int idx = blockIdx.x * blockDim.x + threadIdx.x;
    if (idx < N * DIM) {
        int d = idx & 63;
        node[idx] += coef[d] * agg[idx] + coef[64 + d];
    }
}

// per-graph mean pool (graph_ids sorted -> binary search) + softplus + MLP head
__global__ void k_head(const float* __restrict__ node, const int* __restrict__ gid, int N,
                       const float* __restrict__ Wfc, const float* __restrict__ bfc,
                       const float* __restrict__ Wout, const float* __restrict__ bout,
                       float* __restrict__ out) {
    int g = blockIdx.x;
    __shared__ int bounds[2];
    if (threadIdx.x == 0) {
        int lo = 0, hi = N;
        while (lo < hi) { int mid = (lo + hi) >> 1; if (gid[mid] < g) lo = mid + 1; else hi = mid; }
        bounds[0] = lo;
        int lo2 = lo; hi = N;
        while (lo2 < hi) { int mid = (lo2 + hi) >> 1; if (gid[mid] < g + 1) lo2 = mid + 1; else hi = mid; }
        bounds[1] = lo2;
    }
    __syncthreads();
    int s = bounds[0], e = bounds[1];
    __shared__ float sp[DIM];
    if (threadIdx.x < DIM) {
        float acc = 0.f;
        for (int n = s; n < e; ++n) acc += node[(size_t)n * DIM + threadIdx.x];
        float cntf = (float)max(e - s, 1);
        float m = acc / cntf;
        sp[threadIdx.x] = softplusf_(m);
    }
    __syncthreads();
    int j = threadIdx.x;  // 128 threads
    float hj = bfc[j];
#pragma unroll 8
    for (int k = 0; k < DIM; ++k) hj += sp[k] * Wfc[k * HID + j];
    hj = softplusf_(hj);
    __shared__ float red[HID];
    red[j] = hj * Wout[j];
    __syncthreads();
    for (int off = HID / 2; off > 0; off >>= 1) {
        if (j < off) red[j] += red[j + off];
        __syncthreads();
    }
    if (j == 0) out[g] = red[0] + bout[0];
}

extern "C" void kernel_launch(void* const* d_in, const int* in_sizes, int n_in,
                              void* d_out, int out_size, void* d_ws, size_t ws_size,
                              hipStream_t stream) {
    const int* atom_types = (const int*)d_in[0];
    const int* src = (const int*)d_in[1];
    const int* dst = (const int*)d_in[2];
    const int* gid = (const int*)d_in[3];
    const float* dist = (const float*)d_in[4];
    const float* emb = (const float*)d_in[5];
    const float* W1 = (const float*)d_in[6];
    const float* b1 = (const float*)d_in[7];
    // d_in[8]=W2, d_in[9]=b2: dead (reference bug keeps fc_full2 output unused)
    const float* g1 = (const float*)d_in[10];
    const float* bt1 = (const float*)d_in[11];
    const float* g2 = (const float*)d_in[12];
    const float* bt2 = (const float*)d_in[13];
    const float* g3 = (const float*)d_in[14];
    const float* bt3 = (const float*)d_in[15];
    const float* Wfc = (const float*)d_in[16];
    const float* bfc = (const float*)d_in[17];
    const float* Wout = (const float*)d_in[18];
    const float* bout = (const float*)d_in[19];

    int N = in_sizes[0];
    int E = in_sizes[1];
    int G = out_size;

    char* ws = (char*)d_ws;
    size_t nd = (size_t)N * DIM * sizeof(float);
    float* node = (float*)ws;            ws += nd;
    float* P = (float*)ws;               ws += nd;
    float* Q = (float*)ws;               ws += nd;
    float* agg = (float*)ws;             ws += nd;
    float* T = (float*)ws;               ws += (size_t)NCONV * TB * DIM * sizeof(float);
    double* stats = (double*)ws;         ws += (size_t)NCONV * 3 * 128 * sizeof(double);
    float* coef = (float*)ws;            ws += (size_t)NCONV * 3 * 128 * sizeof(float);

    // zero all stats accumulators once
    hipMemsetAsync(stats, 0, (size_t)NCONV * 3 * 128 * sizeof(double), stream);

    k_embed<<<(N * DIM + 255) / 256, 256, 0, stream>>>(atom_types, emb, node, N);
    k_tables<<<NCONV * TB, 64, 0, stream>>>(W1, T);

    for (int l = 0; l < NCONV; ++l) {
        const float* Tl = T + (size_t)l * TB * DIM;
        const float* b1l = b1 + l * DIM;
        double* st1 = stats + (size_t)(l * 3 + 0) * 128;
        double* st2 = stats + (size_t)(l * 3 + 1) * 128;
        double* st3 = stats + (size_t)(l * 3 + 2) * 128;
        float* cf1 = coef + (size_t)(l * 3 + 0) * 128;
        float* cf2 = coef + (size_t)(l * 3 + 1) * 128;
        float* cf3 = coef + (size_t)(l * 3 + 2) * 128;

        k_nodepq<<<2048, 256, 0, stream>>>(node, W1, l, P, Q, N);

        k_edge<1><<<1024, 256, 0, stream>>>(src, dst, dist, P, Q, Tl, b1l,
                                            nullptr, nullptr, st1, nullptr, E);
        k_finalize<<<1, 64, 0, stream>>>(st1, g1 + l * DIM, bt1 + l * DIM, 1.0 / E, cf1);

        k_edge<2><<<1024, 256, 0, stream>>>(src, dst, dist, P, Q, Tl, b1l,
                                            cf1, nullptr, st2, nullptr, E);
        k_finalize<<<1, 64, 0, stream>>>(st2, g2 + l * DIM, bt2 + l * DIM, 1.0 / E, cf2);

        hipMemsetAsync(agg, 0, nd, stream);
        k_edge<3><<<1024, 256, 0, stream>>>(src, dst, dist, P, Q, Tl, b1l,
                                            cf1, cf2, nullptr, agg, E);

        k_nodestats<<<1024, 256, 0, stream>>>(agg, st3, N);
        k_finalize<<<1, 64, 0, stream>>>(st3, g3 + l * DIM, bt3 + l * DIM, 1.0 / N, cf3);
        k_nodeupd<<<(N * DIM + 255) / 256, 256, 0, stream>>>(node, agg, cf3, N);
    }

    k_head<<<G, HID, 0, stream>>>(node, gid, N, Wfc, bfc, Wout, bout, (float*)d_out);
}

// Round 2
// 1452.863 us; speedup vs baseline: 1.6753x; 1.6753x over previous
//
#include <hip/hip_runtime.h>
#include <math.h>

#define DIM 64
#define NG 64
#define CIN 192
#define HID 128
#define NCONV 3
#define TB 8192
#define CUTOFF 12.0f
#define EPS 1e-5f
#define SCB 256

__device__ __forceinline__ float sp_(float y) {
    // softplus: max(y,0) + log(1 + exp(-|y|))
    return fmaxf(y, 0.f) + __logf(1.f + __expf(-fabsf(y)));
}
__device__ __forceinline__ float sig_(float y) {
    return 1.f / (1.f + __expf(-y));
}

// node[n][d] = embed_table[atom_types[n]][d]
__global__ void k_embed(const int* __restrict__ at, const float* __restrict__ emb,
                        float* __restrict__ node, int N) {
    int idx = blockIdx.x * blockDim.x + threadIdx.x;
    if (idx < N * DIM) {
        int n = idx >> 6, d = idx & 63;
        node[idx] = emb[at[n] * DIM + d];
    }
}

// T[l][i][d] = sum_g exp(coeff*(x_i-mu_g)^2) * W1[l][128+g][d]
__global__ void k_tables(const float* __restrict__ W1, float* __restrict__ T) {
    int row = blockIdx.x;            // 0 .. 3*TB-1
    int l = row / TB, i = row % TB;
    int d = threadIdx.x;             // 64 threads
    const float stepmu = CUTOFF / (float)(NG - 1);
    const float coeff = -0.5f / (stepmu * stepmu);
    float x = (float)i * (CUTOFF / (float)(TB - 1));
    __shared__ float rbf[NG];
    float mu = (float)d * stepmu;
    float diff = x - mu;
    rbf[d] = expf(coeff * diff * diff);
    __syncthreads();
    const float* w = W1 + (size_t)(l * CIN + 2 * DIM) * DIM;
    float acc = 0.f;
#pragma unroll 8
    for (int g = 0; g < NG; ++g) acc += rbf[g] * w[g * DIM + d];
    T[(size_t)row * DIM + d] = acc;
}

// ---- CSR build (dst-sorted edge permutation; dst fixed across layers) ----
__global__ void k_hist(const int* __restrict__ dst, int* __restrict__ cnt, int E) {
    for (int e = blockIdx.x * blockDim.x + threadIdx.x; e < E;
         e += gridDim.x * blockDim.x)
        atomicAdd(&cnt[dst[e]], 1);
}

__global__ void k_scanA(const int* __restrict__ cnt, int* __restrict__ bsum, int N) {
    __shared__ int lds[SCB];
    int i = blockIdx.x * SCB + threadIdx.x;
    lds[threadIdx.x] = (i < N) ? cnt[i] : 0;
    __syncthreads();
    for (int o = SCB / 2; o > 0; o >>= 1) {
        if (threadIdx.x < o) lds[threadIdx.x] += lds[threadIdx.x + o];
        __syncthreads();
    }
    if (threadIdx.x == 0) bsum[blockIdx.x] = lds[0];
}

__global__ void k_scanB(const int* __restrict__ bsum, int* __restrict__ bexcl, int NB) {
    __shared__ int lds[SCB];
    int t = threadIdx.x;
    int v = (t < NB) ? bsum[t] : 0;
    lds[t] = v;
    __syncthreads();
    for (int o = 1; o < SCB; o <<= 1) {
        int add = (t >= o) ? lds[t - o] : 0;
        __syncthreads();
        lds[t] += add;
        __syncthreads();
    }
    if (t < NB) bexcl[t] = lds[t] - v;   // exclusive
}

__global__ void k_scanC(const int* __restrict__ cnt, const int* __restrict__ bexcl,
                        int* __restrict__ off, int* __restrict__ cursor, int N, int E) {
    __shared__ int lds[SCB];
    int t = threadIdx.x;
    int i = blockIdx.x * SCB + t;
    int v = (i < N) ? cnt[i] : 0;
    lds[t] = v;
    __syncthreads();
    for (int o = 1; o < SCB; o <<= 1) {
        int add = (t >= o) ? lds[t - o] : 0;
        __syncthreads();
        lds[t] += add;
        __syncthreads();
    }
    if (i < N) {
        int excl = bexcl[blockIdx.x] + lds[t] - v;
        off[i] = excl;
        cursor[i] = excl;
        if (i == N - 1) off[N] = E;
    }
}

__global__ void k_scatter(const int* __restrict__ src, const int* __restrict__ dst,
                          const float* __restrict__ dist, int* __restrict__ cursor,
                          int* __restrict__ src_s, float* __restrict__ dist_s, int E) {
    for (int e = blockIdx.x * blockDim.x + threadIdx.x; e < E;
         e += gridDim.x * blockDim.x) {
        int t = dst[e];
        int pos = atomicAdd(&cursor[t], 1);
        src_s[pos] = src[e];
        dist_s[pos] = dist[e];
    }
}

// P = node @ W1[l][0:64], Q = node @ W1[l][64:128]
__global__ void k_nodepq(const float* __restrict__ node, const float* __restrict__ W1, int l,
                         float* __restrict__ P, float* __restrict__ Q, int N) {
    __shared__ float wa[DIM * DIM];
    __shared__ float wb[DIM * DIM];
    const float* WA = W1 + (size_t)(l * CIN) * DIM;
    for (int k = threadIdx.x; k < DIM * DIM; k += blockDim.x) {
        wa[k] = WA[k];
        wb[k] = WA[DIM * DIM + k];
    }
    __syncthreads();
    int lane = threadIdx.x & 63, w = threadIdx.x >> 6;
    int wpb = blockDim.x >> 6;
    for (int n = blockIdx.x * wpb + w; n < N; n += gridDim.x * wpb) {
        float nv = node[(size_t)n * DIM + lane];
        float ap = 0.f, aq = 0.f;
#pragma unroll 8
        for (int k = 0; k < DIM; ++k) {
            float b = __shfl(nv, k);
            ap += b * wa[k * DIM + lane];
            aq += b * wb[k * DIM + lane];
        }
        P[(size_t)n * DIM + lane] = ap;
        Q[(size_t)n * DIM + lane] = aq;
    }
}

// CSR conv kernel, wave-per-node (Q[dst]+b1 hoisted per segment).
// MODE 0: stats(z).  MODE 1: stats(z) + write z.
// MODE 2: stats(f=sigmoid(bn1(z))) (recompute path).
// MODE 3: h = f*softplus(bn2(f)), register-accumulate -> agg + node stats.
template <int MODE>
__global__ void k_conv(const int* __restrict__ off, const int* __restrict__ src_s,
                       const float* __restrict__ dist_s,
                       const float* __restrict__ P, const float* __restrict__ Q,
                       const float* __restrict__ T, const float* __restrict__ b1,
                       const float* __restrict__ coef1, const float* __restrict__ coef2,
                       double* __restrict__ stats, float* __restrict__ zf,
                       float* __restrict__ agg, int N) {
    int lane = threadIdx.x & 63;
    int w = threadIdx.x >> 6;
    int wpb = blockDim.x >> 6;
    float bv = b1[lane];
    float a1 = 0.f, c1 = 0.f, a2 = 0.f, c2 = 0.f;
    if (MODE >= 2) { a1 = coef1[lane]; c1 = coef1[64 + lane]; }
    if (MODE == 3) { a2 = coef2[lane]; c2 = coef2[64 + lane]; }
    const float inv_step = (float)(TB - 1) / CUTOFF;
    float s0 = 0.f, s1 = 0.f;
    for (int n = blockIdx.x * wpb + w; n < N; n += gridDim.x * wpb) {
        int e0 = off[n], e1 = off[n + 1];
        float qc = Q[(size_t)n * DIM + lane] + bv;
        float acc = 0.f;
        for (int e = e0; e < e1; ++e) {
            float x = dist_s[e];
            int s = src_s[e];
            float u = x * inv_step;
            int i = (int)u;
            i = max(0, min(i, TB - 2));
            float fr = u - (float)i;
            float t0 = T[(size_t)i * DIM + lane];
            float t1 = T[(size_t)(i + 1) * DIM + lane];
            float z = P[(size_t)s * DIM + lane] + t0 + fr * (t1 - t0) + qc;
            if (MODE <= 1) {
                s0 += z; s1 += z * z;
                if (MODE == 1) zf[(size_t)e * DIM + lane] = z;
            } else {
                float f = sig_(a1 * z + c1);
                if (MODE == 2) { s0 += f; s1 += f * f; }
                else acc += f * sp_(a2 * f + c2);
            }
        }
        if (MODE == 3) {
            agg[(size_t)n * DIM + lane] = acc;
            s0 += acc; s1 += acc * acc;
        }
    }
    __shared__ float r0[4][64];
    __shared__ float r1[4][64];
    r0[w][lane] = s0;
    r1[w][lane] = s1;
    __syncthreads();
    if (threadIdx.x < 64) {
        float t0 = 0.f, t1 = 0.f;
        for (int q = 0; q < wpb; ++q) { t0 += r0[q][threadIdx.x]; t1 += r1[q][threadIdx.x]; }
        atomicAdd(&stats[threadIdx.x], (double)t0);
        atomicAdd(&stats[64 + threadIdx.x], (double)t1);
    }
}

// streaming: f = sigmoid(a1*z + c1) in place, stats(f). float4 per thread.
__global__ void k_sig(float* __restrict__ zf, const float* __restrict__ coef1,
                      double* __restrict__ stats, long long total4) {
    long long tid = (long long)blockIdx.x * blockDim.x + threadIdx.x;
    long long stride = (long long)gridDim.x * blockDim.x;   // multiple of 16
    int g = threadIdx.x & 15;                               // dim group (4 dims)
    float a1[4], c1[4];
#pragma unroll
    for (int q = 0; q < 4; ++q) { a1[q] = coef1[g * 4 + q]; c1[q] = coef1[64 + g * 4 + q]; }
    float s0[4] = {0, 0, 0, 0}, s1[4] = {0, 0, 0, 0};
    float4* z4 = (float4*)zf;
    for (long long i = tid; i < total4; i += stride) {
        float4 v = z4[i];
        float f0 = sig_(a1[0] * v.x + c1[0]);
        float f1 = sig_(a1[1] * v.y + c1[1]);
        float f2 = sig_(a1[2] * v.z + c1[2]);
        float f3 = sig_(a1[3] * v.w + c1[3]);
        s0[0] += f0; s1[0] += f0 * f0;
        s0[1] += f1; s1[1] += f1 * f1;
        s0[2] += f2; s1[2] += f2 * f2;
        s0[3] += f3; s1[3] += f3 * f3;
        z4[i] = make_float4(f0, f1, f2, f3);
    }
    __shared__ float lds[256][8];
#pragma unroll
    for (int q = 0; q < 4; ++q) { lds[threadIdx.x][q] = s0[q]; lds[threadIdx.x][4 + q] = s1[q]; }
    __syncthreads();
    if (threadIdx.x < 64) {
        int d = threadIdx.x;
        float t0 = 0.f, t1 = 0.f;
        for (int k = 0; k < 16; ++k) {
            t0 += lds[(d >> 2) + 16 * k][d & 3];
            t1 += lds[(d >> 2) + 16 * k][4 + (d & 3)];
        }
        atomicAdd(&stats[d], (double)t0);
        atomicAdd(&stats[64 + d], (double)t1);
    }
}

// plan M phase 3: read f (dst-grouped, sequential), h, register segment-reduce.
__global__ void k_aggf(const int* __restrict__ off, const float* __restrict__ F,
                       const float* __restrict__ coef2, double* __restrict__ stats,
                       float* __restrict__ agg, int N) {
    int lane = threadIdx.x & 63;
    int w = threadIdx.x >> 6;
    int wpb = blockDim.x >> 6;
    float a2 = coef2[lane], c2 = coef2[64 + lane];
    float s0 = 0.f, s1 = 0.f;
    for (int n = blockIdx.x * wpb + w; n < N; n += gridDim.x * wpb) {
        int e0 = off[n], e1 = off[n + 1];
        float acc = 0.f;
        for (int e = e0; e < e1; ++e) {
            float f = F[(size_t)e * DIM + lane];
            acc += f * sp_(a2 * f + c2);
        }
        agg[(size_t)n * DIM + lane] = acc;
        s0 += acc; s1 += acc * acc;
    }
    __shared__ float r0[4][64];
    __shared__ float r1[4][64];
    r0[w][lane] = s0;
    r1[w][lane] = s1;
    __syncthreads();
    if (threadIdx.x < 64) {
        float t0 = 0.f, t1 = 0.f;
        for (int q = 0; q < wpb; ++q) { t0 += r0[q][threadIdx.x]; t1 += r1[q][threadIdx.x]; }
        atomicAdd(&stats[threadIdx.x], (double)t0);
        atomicAdd(&stats[64 + threadIdx.x], (double)t1);
    }
}

// m=sum/cnt, v=sq/cnt-m^2; a=g/sqrt(v+eps), c=bt-a*m
__global__ void k_finalize(const double* __restrict__ stats, const float* __restrict__ g,
                           const float* __restrict__ bt, double invcnt, float* __restrict__ coef) {
    int d = threadIdx.x;  // 64 threads
    double m = stats[d] * invcnt;
    double v = stats[64 + d] * invcnt - m * m;
    float a = g[d] / sqrtf((float)v + EPS);
    coef[d] = a;
    coef[64 + d] = bt[d] - a * (float)m;
}

__global__ void k_nodeupd(float* __restrict__ node, const float* __restrict__ agg,
                          const float* __restrict__ coef, int N) {
    int idx = blockIdx.x * blockDim.x + threadIdx.x;
    if (idx < N * DIM) {
        int d = idx & 63;
        node[idx] += coef[d] * agg[idx] + coef[64 + d];
    }
}

// per-graph mean pool (graph_ids sorted -> binary search) + softplus + MLP head
__global__ void k_head(const float* __restrict__ node, const int* __restrict__ gid, int N,
                       const float* __restrict__ Wfc, const float* __restrict__ bfc,
                       const float* __restrict__ Wout, const float* __restrict__ bout,
                       float* __restrict__ out) {
    int g = blockIdx.x;
    __shared__ int bounds[2];
    if (threadIdx.x == 0) {
        int lo = 0, hi = N;
        while (lo < hi) { int mid = (lo + hi) >> 1; if (gid[mid] < g) lo = mid + 1; else hi = mid; }
        bounds[0] = lo;
        int lo2 = lo; hi = N;
        while (lo2 < hi) { int mid = (lo2 + hi) >> 1; if (gid[mid] < g + 1) lo2 = mid + 1; else hi = mid; }
        bounds[1] = lo2;
    }
    __syncthreads();
    int s = bounds[0], e = bounds[1];
    __shared__ float sp[DIM];
    if (threadIdx.x < DIM) {
        float acc = 0.f;
        for (int n = s; n < e; ++n) acc += node[(size_t)n * DIM + threadIdx.x];
        float cntf = (float)max(e - s, 1);
        float m = acc / cntf;
        sp[threadIdx.x] = (m > 0.f) ? m + log1pf(expf(-m)) : log1pf(expf(m));
    }
    __syncthreads();
    int j = threadIdx.x;  // 128 threads
    float hj = bfc[j];
#pragma unroll 8
    for (int k = 0; k < DIM; ++k) hj += sp[k] * Wfc[k * HID + j];
    hj = (hj > 0.f) ? hj + log1pf(expf(-hj)) : log1pf(expf(hj));
    __shared__ float red[HID];
    red[j] = hj * Wout[j];
    __syncthreads();
    for (int o = HID / 2; o > 0; o >>= 1) {
        if (j < o) red[j] += red[j + o];
        __syncthreads();
    }
    if (j == 0) out[g] = red[0] + bout[0];
}

extern "C" void kernel_launch(void* const* d_in, const int* in_sizes, int n_in,
                              void* d_out, int out_size, void* d_ws, size_t ws_size,
                              hipStream_t stream) {
    const int* atom_types = (const int*)d_in[0];
    const int* src = (const int*)d_in[1];
    const int* dst = (const int*)d_in[2];
    const int* gid = (const int*)d_in[3];
    const float* dist = (const float*)d_in[4];
    const float* emb = (const float*)d_in[5];
    const float* W1 = (const float*)d_in[6];
    const float* b1 = (const float*)d_in[7];
    // d_in[8]=W2, d_in[9]=b2: dead (reference bug: fc_full2 output unused)
    const float* g1 = (const float*)d_in[10];
    const float* bt1 = (const float*)d_in[11];
    const float* g2 = (const float*)d_in[12];
    const float* bt2 = (const float*)d_in[13];
    const float* g3 = (const float*)d_in[14];
    const float* bt3 = (const float*)d_in[15];
    const float* Wfc = (const float*)d_in[16];
    const float* bfc = (const float*)d_in[17];
    const float* Wout = (const float*)d_in[18];
    const float* bout = (const float*)d_in[19];

    int N = in_sizes[0];
    int E = in_sizes[1];
    int G = out_size;
    int NB = (N + SCB - 1) / SCB;   // <= 256 for N <= 65536

    char* ws = (char*)d_ws;
    auto alloc = [&](size_t bytes) -> char* {
        char* p = ws;
        ws += (bytes + 255) & ~(size_t)255;
        return p;
    };
    size_t nd = (size_t)N * DIM * sizeof(float);
    float* node = (float*)alloc(nd);
    float* P = (float*)alloc(nd);
    float* Q = (float*)alloc(nd);
    float* agg = (float*)alloc(nd);
    float* T = (float*)alloc((size_t)NCONV * TB * DIM * sizeof(float));
    double* stats = (double*)alloc((size_t)NCONV * 3 * 128 * sizeof(double));
    float* coef = (float*)alloc((size_t)NCONV * 3 * 128 * sizeof(float));
    int* off = (int*)alloc((size_t)(N + 1) * sizeof(int));
    int* cursor = (int*)alloc((size_t)N * sizeof(int));
    int* cnt = (int*)alloc((size_t)N * sizeof(int));
    int* bsum = (int*)alloc(SCB * sizeof(int));
    int* bexcl = (int*)alloc(SCB * sizeof(int));
    int* src_s = (int*)alloc((size_t)E * sizeof(int));
    float* dist_s = (float*)alloc((size_t)E * sizeof(float));
    size_t fbytes = (size_t)E * DIM * sizeof(float);
    size_t used = (size_t)(ws - (char*)d_ws);
    bool planM = (used + fbytes) <= ws_size;
    float* F = planM ? (float*)alloc(fbytes) : nullptr;

    hipMemsetAsync(stats, 0, (size_t)NCONV * 3 * 128 * sizeof(double), stream);
    hipMemsetAsync(cnt, 0, (size_t)N * sizeof(int), stream);

    k_embed<<<(N * DIM + 255) / 256, 256, 0, stream>>>(atom_types, emb, node, N);
    k_tables<<<NCONV * TB, 64, 0, stream>>>(W1, T);

    // CSR build (dst-sorted)
    k_hist<<<1024, 256, 0, stream>>>(dst, cnt, E);
    k_scanA<<<NB, SCB, 0, stream>>>(cnt, bsum, N);
    k_scanB<<<1, SCB, 0, stream>>>(bsum, bexcl, NB);
    k_scanC<<<NB, SCB, 0, stream>>>(cnt, bexcl, off, cursor, N, E);
    k_scatter<<<1024, 256, 0, stream>>>(src, dst, dist, cursor, src_s, dist_s, E);

    for (int l = 0; l < NCONV; ++l) {
        const float* Tl = T + (size_t)l * TB * DIM;
        const float* b1l = b1 + l * DIM;
        double* st1 = stats + (size_t)(l * 3 + 0) * 128;
        double* st2 = stats + (size_t)(l * 3 + 1) * 128;
        double* st3 = stats + (size_t)(l * 3 + 2) * 128;
        float* cf1 = coef + (size_t)(l * 3 + 0) * 128;
        float* cf2 = coef + (size_t)(l * 3 + 1) * 128;
        float* cf3 = coef + (size_t)(l * 3 + 2) * 128;

        k_nodepq<<<2048, 256, 0, stream>>>(node, W1, l, P, Q, N);

        if (planM) {
            k_conv<1><<<2048, 256, 0, stream>>>(off, src_s, dist_s, P, Q, Tl, b1l,
                                                nullptr, nullptr, st1, F, nullptr, N);
            k_finalize<<<1, 64, 0, stream>>>(st1, g1 + l * DIM, bt1 + l * DIM, 1.0 / E, cf1);
            k_sig<<<2048, 256, 0, stream>>>(F, cf1, st2, (long long)E * DIM / 4);
            k_finalize<<<1, 64, 0, stream>>>(st2, g2 + l * DIM, bt2 + l * DIM, 1.0 / E, cf2);
            k_aggf<<<2048, 256, 0, stream>>>(off, F, cf2, st3, agg, N);
        } else {
            k_conv<0><<<2048, 256, 0, stream>>>(off, src_s, dist_s, P, Q, Tl, b1l,
                                                nullptr, nullptr, st1, nullptr, nullptr, N);
            k_finalize<<<1, 64, 0, stream>>>(st1, g1 + l * DIM, bt1 + l * DIM, 1.0 / E, cf1);
            k_conv<2><<<2048, 256, 0, stream>>>(off, src_s, dist_s, P, Q, Tl, b1l,
                                                cf1, nullptr, st2, nullptr, nullptr, N);
            k_finalize<<<1, 64, 0, stream>>>(st2, g2 + l * DIM, bt2 + l * DIM, 1.0 / E, cf2);
            k_conv<3><<<2048, 256, 0, stream>>>(off, src_s, dist_s, P, Q, Tl, b1l,
                                                cf1, cf2, st3, nullptr, agg, N);
        }

        k_finalize<<<1, 64, 0, stream>>>(st3, g3 + l * DIM, bt3 + l * DIM, 1.0 / N, cf3);
        k_nodeupd<<<(N * DIM + 255) / 256, 256, 0, stream>>>(node, agg, cf3, N);
    }

    k_head<<<G, HID, 0, stream>>>(node, gid, N, Wfc, bfc, Wout, bout, (float*)d_out);
}

// Round 3
// 1212.279 us; speedup vs baseline: 2.0078x; 1.1985x over previous
//
#include <hip/hip_runtime.h>
#include <math.h>

#define DIM 64
#define NG 64
#define CIN 192
#define HID 128
#define NCONV 3
#define TB 8192
#define CUTOFF 12.0f
#define EPS 1e-5f
#define SCB 256

__device__ __forceinline__ float sp_(float y) {
    // softplus: max(y,0) + log(1 + exp(-|y|))
    return fmaxf(y, 0.f) + __logf(1.f + __expf(-fabsf(y)));
}
__device__ __forceinline__ float sig_(float y) {
    return 1.f / (1.f + __expf(-y));
}

// node[n][d] = embed_table[atom_types[n]][d]
__global__ void k_embed(const int* __restrict__ at, const float* __restrict__ emb,
                        float* __restrict__ node, int N) {
    int idx = blockIdx.x * blockDim.x + threadIdx.x;
    if (idx < N * DIM) {
        int n = idx >> 6, d = idx & 63;
        node[idx] = emb[at[n] * DIM + d];
    }
}

// T[l][i][d] = sum_g exp(coeff*(x_i-mu_g)^2) * W1[l][128+g][d]
__global__ void k_tables(const float* __restrict__ W1, float* __restrict__ T) {
    int row = blockIdx.x;            // 0 .. 3*TB-1
    int l = row / TB, i = row % TB;
    int d = threadIdx.x;             // 64 threads
    const float stepmu = CUTOFF / (float)(NG - 1);
    const float coeff = -0.5f / (stepmu * stepmu);
    float x = (float)i * (CUTOFF / (float)(TB - 1));
    __shared__ float rbf[NG];
    float mu = (float)d * stepmu;
    float diff = x - mu;
    rbf[d] = expf(coeff * diff * diff);
    __syncthreads();
    const float* w = W1 + (size_t)(l * CIN + 2 * DIM) * DIM;
    float acc = 0.f;
#pragma unroll 8
    for (int g = 0; g < NG; ++g) acc += rbf[g] * w[g * DIM + d];
    T[(size_t)row * DIM + d] = acc;
}

// ---- CSR build (dst-sorted edge permutation; dst fixed across layers) ----
__global__ void k_hist(const int* __restrict__ dst, int* __restrict__ cnt, int E) {
    for (int e = blockIdx.x * blockDim.x + threadIdx.x; e < E;
         e += gridDim.x * blockDim.x)
        atomicAdd(&cnt[dst[e]], 1);
}

__global__ void k_scanA(const int* __restrict__ cnt, int* __restrict__ bsum, int N) {
    __shared__ int lds[SCB];
    int i = blockIdx.x * SCB + threadIdx.x;
    lds[threadIdx.x] = (i < N) ? cnt[i] : 0;
    __syncthreads();
    for (int o = SCB / 2; o > 0; o >>= 1) {
        if (threadIdx.x < o) lds[threadIdx.x] += lds[threadIdx.x + o];
        __syncthreads();
    }
    if (threadIdx.x == 0) bsum[blockIdx.x] = lds[0];
}

__global__ void k_scanB(const int* __restrict__ bsum, int* __restrict__ bexcl, int NB) {
    __shared__ int lds[SCB];
    int t = threadIdx.x;
    int v = (t < NB) ? bsum[t] : 0;
    lds[t] = v;
    __syncthreads();
    for (int o = 1; o < SCB; o <<= 1) {
        int add = (t >= o) ? lds[t - o] : 0;
        __syncthreads();
        lds[t] += add;
        __syncthreads();
    }
    if (t < NB) bexcl[t] = lds[t] - v;   // exclusive
}

__global__ void k_scanC(const int* __restrict__ cnt, const int* __restrict__ bexcl,
                        int* __restrict__ off, int* __restrict__ cursor, int N, int E) {
    __shared__ int lds[SCB];
    int t = threadIdx.x;
    int i = blockIdx.x * SCB + t;
    int v = (i < N) ? cnt[i] : 0;
    lds[t] = v;
    __syncthreads();
    for (int o = 1; o < SCB; o <<= 1) {
        int add = (t >= o) ? lds[t - o] : 0;
        __syncthreads();
        lds[t] += add;
        __syncthreads();
    }
    if (i < N) {
        int excl = bexcl[blockIdx.x] + lds[t] - v;
        off[i] = excl;
        cursor[i] = excl;
        if (i == N - 1) off[N] = E;
    }
}

// scatter edges into dst-sorted order; pack (src, dist*inv_step) as int2
__global__ void k_scatter(const int* __restrict__ src, const int* __restrict__ dst,
                          const float* __restrict__ dist, int* __restrict__ cursor,
                          int2* __restrict__ es, int E) {
    const float inv_step = (float)(TB - 1) / CUTOFF;
    for (int e = blockIdx.x * blockDim.x + threadIdx.x; e < E;
         e += gridDim.x * blockDim.x) {
        int t = dst[e];
        int pos = atomicAdd(&cursor[t], 1);
        es[pos] = make_int2(src[e], __float_as_int(dist[e] * inv_step));
    }
}

// P = node @ W1[l][0:64], Q = node @ W1[l][64:128]
__global__ void k_nodepq(const float* __restrict__ node, const float* __restrict__ W1, int l,
                         float* __restrict__ P, float* __restrict__ Q, int N) {
    __shared__ float wa[DIM * DIM];
    __shared__ float wb[DIM * DIM];
    const float* WA = W1 + (size_t)(l * CIN) * DIM;
    for (int k = threadIdx.x; k < DIM * DIM; k += blockDim.x) {
        wa[k] = WA[k];
        wb[k] = WA[DIM * DIM + k];
    }
    __syncthreads();
    int lane = threadIdx.x & 63, w = threadIdx.x >> 6;
    int wpb = blockDim.x >> 6;
    for (int n = blockIdx.x * wpb + w; n < N; n += gridDim.x * wpb) {
        float nv = node[n * DIM + lane];
        float ap = 0.f, aq = 0.f;
#pragma unroll 8
        for (int k = 0; k < DIM; ++k) {
            float b = __shfl(nv, k);
            ap += b * wa[k * DIM + lane];
            aq += b * wb[k * DIM + lane];
        }
        P[n * DIM + lane] = ap;
        Q[n * DIM + lane] = aq;
    }
}

// CSR conv pass, wave-per-node, BN coefficients computed inline from stats.
// MODE 0: stats(z).
// MODE 2: stats(f=sigmoid(bn1(z))).
// MODE 3: agg[n] = sum_e f*softplus(bn2(f)); node stats of agg.
template <int MODE>
__global__ void __launch_bounds__(256) k_conv(
        const int* __restrict__ off, const int2* __restrict__ es,
        const float* __restrict__ P, const float* __restrict__ Q,
        const float* __restrict__ T, const float* __restrict__ b1,
        const double* __restrict__ stA, const float* __restrict__ gA,
        const float* __restrict__ btA,
        const double* __restrict__ stB, const float* __restrict__ gB,
        const float* __restrict__ btB,
        double* __restrict__ stats, float* __restrict__ agg, int N, double invE) {
    int lane = threadIdx.x & 63;
    int w = threadIdx.x >> 6;
    float bv = b1[lane];
    float a1 = 0.f, c1 = 0.f, a2 = 0.f, c2 = 0.f;
    if (MODE >= 2) {
        double m = stA[lane] * invE;
        double v = stA[64 + lane] * invE - m * m;
        a1 = gA[lane] / sqrtf((float)v + EPS);
        c1 = btA[lane] - a1 * (float)m;
    }
    if (MODE == 3) {
        double m = stB[lane] * invE;
        double v = stB[64 + lane] * invE - m * m;
        a2 = gB[lane] / sqrtf((float)v + EPS);
        c2 = btB[lane] - a2 * (float)m;
    }
    float s0 = 0.f, s1 = 0.f;
    int gw = blockIdx.x * 4 + w, nw = gridDim.x * 4;
    for (int n = gw; n < N; n += nw) {
        int e0 = off[n], e1 = off[n + 1];
        float qc = Q[n * DIM + lane] + bv;
        float acc = 0.f;
        int e = e0;
        for (; e + 2 <= e1; e += 2) {
            int2 eA = es[e], eB = es[e + 1];
            float uA = __int_as_float(eA.y), uB = __int_as_float(eB.y);
            int iA = (int)uA, iB = (int)uB;
            iA = max(0, min(iA, TB - 2));
            iB = max(0, min(iB, TB - 2));
            float frA = uA - (float)iA, frB = uB - (float)iB;
            const float* tA = T + iA * DIM + lane;
            const float* tB = T + iB * DIM + lane;
            float tA0 = tA[0], tA1 = tA[DIM];
            float tB0 = tB[0], tB1 = tB[DIM];
            float pA = P[eA.x * DIM + lane];
            float pB = P[eB.x * DIM + lane];
            float zA = pA + tA0 + frA * (tA1 - tA0) + qc;
            float zB = pB + tB0 + frB * (tB1 - tB0) + qc;
            if (MODE == 0) {
                s0 += zA + zB; s1 += zA * zA + zB * zB;
            } else {
                float fA = sig_(a1 * zA + c1);
                float fB = sig_(a1 * zB + c1);
                if (MODE == 2) { s0 += fA + fB; s1 += fA * fA + fB * fB; }
                else acc += fA * sp_(a2 * fA + c2) + fB * sp_(a2 * fB + c2);
            }
        }
        if (e < e1) {
            int2 eA = es[e];
            float uA = __int_as_float(eA.y);
            int iA = (int)uA;
            iA = max(0, min(iA, TB - 2));
            float frA = uA - (float)iA;
            const float* tA = T + iA * DIM + lane;
            float tA0 = tA[0], tA1 = tA[DIM];
            float pA = P[eA.x * DIM + lane];
            float zA = pA + tA0 + frA * (tA1 - tA0) + qc;
            if (MODE == 0) {
                s0 += zA; s1 += zA * zA;
            } else {
                float fA = sig_(a1 * zA + c1);
                if (MODE == 2) { s0 += fA; s1 += fA * fA; }
                else acc += fA * sp_(a2 * fA + c2);
            }
        }
        if (MODE == 3) {
            agg[n * DIM + lane] = acc;
            s0 += acc; s1 += acc * acc;
        }
    }
    __shared__ float r0[4][64];
    __shared__ float r1[4][64];
    r0[w][lane] = s0;
    r1[w][lane] = s1;
    __syncthreads();
    if (threadIdx.x < 64) {
        int d = threadIdx.x;
        float t0 = r0[0][d] + r0[1][d] + r0[2][d] + r0[3][d];
        float t1 = r1[0][d] + r1[1][d] + r1[2][d] + r1[3][d];
        atomicAdd(&stats[d], (double)t0);
        atomicAdd(&stats[64 + d], (double)t1);
    }
}

// node += bn3(agg), coefficients computed inline from st3
__global__ void k_nodeupd(float* __restrict__ node, const float* __restrict__ agg,
                          const double* __restrict__ st, const float* __restrict__ g,
                          const float* __restrict__ bt, double invN, int N) {
    int idx = blockIdx.x * blockDim.x + threadIdx.x;
    if (idx < N * DIM) {
        int d = idx & 63;
        double m = st[d] * invN;
        double v = st[64 + d] * invN - m * m;
        float a = g[d] / sqrtf((float)v + EPS);
        float c = bt[d] - a * (float)m;
        node[idx] += a * agg[idx] + c;
    }
}

// per-graph mean pool (graph_ids sorted -> binary search) + softplus + MLP head
__global__ void k_head(const float* __restrict__ node, const int* __restrict__ gid, int N,
                       const float* __restrict__ Wfc, const float* __restrict__ bfc,
                       const float* __restrict__ Wout, const float* __restrict__ bout,
                       float* __restrict__ out) {
    int g = blockIdx.x;
    __shared__ int bounds[2];
    if (threadIdx.x == 0) {
        int lo = 0, hi = N;
        while (lo < hi) { int mid = (lo + hi) >> 1; if (gid[mid] < g) lo = mid + 1; else hi = mid; }
        bounds[0] = lo;
        int lo2 = lo; hi = N;
        while (lo2 < hi) { int mid = (lo2 + hi) >> 1; if (gid[mid] < g + 1) lo2 = mid + 1; else hi = mid; }
        bounds[1] = lo2;
    }
    __syncthreads();
    int s = bounds[0], e = bounds[1];
    __shared__ float sp[DIM];
    if (threadIdx.x < DIM) {
        float acc = 0.f;
        for (int n = s; n < e; ++n) acc += node[(size_t)n * DIM + threadIdx.x];
        float cntf = (float)max(e - s, 1);
        float m = acc / cntf;
        sp[threadIdx.x] = (m > 0.f) ? m + log1pf(expf(-m)) : log1pf(expf(m));
    }
    __syncthreads();
    int j = threadIdx.x;  // 128 threads
    float hj = bfc[j];
#pragma unroll 8
    for (int k = 0; k < DIM; ++k) hj += sp[k] * Wfc[k * HID + j];
    hj = (hj > 0.f) ? hj + log1pf(expf(-hj)) : log1pf(expf(hj));
    __shared__ float red[HID];
    red[j] = hj * Wout[j];
    __syncthreads();
    for (int o = HID / 2; o > 0; o >>= 1) {
        if (j < o) red[j] += red[j + o];
        __syncthreads();
    }
    if (j == 0) out[g] = red[0] + bout[0];
}

extern "C" void kernel_launch(void* const* d_in, const int* in_sizes, int n_in,
                              void* d_out, int out_size, void* d_ws, size_t ws_size,
                              hipStream_t stream) {
    const int* atom_types = (const int*)d_in[0];
    const int* src = (const int*)d_in[1];
    const int* dst = (const int*)d_in[2];
    const int* gid = (const int*)d_in[3];
    const float* dist = (const float*)d_in[4];
    const float* emb = (const float*)d_in[5];
    const float* W1 = (const float*)d_in[6];
    const float* b1 = (const float*)d_in[7];
    // d_in[8]=W2, d_in[9]=b2: dead (reference bug: fc_full2 output unused)
    const float* g1 = (const float*)d_in[10];
    const float* bt1 = (const float*)d_in[11];
    const float* g2 = (const float*)d_in[12];
    const float* bt2 = (const float*)d_in[13];
    const float* g3 = (const float*)d_in[14];
    const float* bt3 = (const float*)d_in[15];
    const float* Wfc = (const float*)d_in[16];
    const float* bfc = (const float*)d_in[17];
    const float* Wout = (const float*)d_in[18];
    const float* bout = (const float*)d_in[19];

    int N = in_sizes[0];
    int E = in_sizes[1];
    int G = out_size;
    int NB = (N + SCB - 1) / SCB;   // <= 256 for N <= 65536

    char* ws = (char*)d_ws;
    auto alloc = [&](size_t bytes) -> char* {
        char* p = ws;
        ws += (bytes + 255) & ~(size_t)255;
        return p;
    };
    size_t nd = (size_t)N * DIM * sizeof(float);
    float* node = (float*)alloc(nd);
    float* P = (float*)alloc(nd);
    float* Q = (float*)alloc(nd);
    float* agg = (float*)alloc(nd);
    float* T = (float*)alloc((size_t)NCONV * TB * DIM * sizeof(float));
    double* stats = (double*)alloc((size_t)NCONV * 3 * 128 * sizeof(double));
    int* off = (int*)alloc((size_t)(N + 1) * sizeof(int));
    int* cursor = (int*)alloc((size_t)N * sizeof(int));
    int* cnt = (int*)alloc((size_t)N * sizeof(int));
    int* bsum = (int*)alloc(SCB * sizeof(int));
    int* bexcl = (int*)alloc(SCB * sizeof(int));
    int2* es = (int2*)alloc((size_t)E * sizeof(int2));

    hipMemsetAsync(stats, 0, (size_t)NCONV * 3 * 128 * sizeof(double), stream);
    hipMemsetAsync(cnt, 0, (size_t)N * sizeof(int), stream);

    k_embed<<<(N * DIM + 255) / 256, 256, 0, stream>>>(atom_types, emb, node, N);
    k_tables<<<NCONV * TB, 64, 0, stream>>>(W1, T);

    // CSR build (dst-sorted)
    k_hist<<<1024, 256, 0, stream>>>(dst, cnt, E);
    k_scanA<<<NB, SCB, 0, stream>>>(cnt, bsum, N);
    k_scanB<<<1, SCB, 0, stream>>>(bsum, bexcl, NB);
    k_scanC<<<NB, SCB, 0, stream>>>(cnt, bexcl, off, cursor, N, E);
    k_scatter<<<1024, 256, 0, stream>>>(src, dst, dist, cursor, es, E);

    double invE = 1.0 / (double)E;
    double invN = 1.0 / (double)N;

    for (int l = 0; l < NCONV; ++l) {
        const float* Tl = T + (size_t)l * TB * DIM;
        const float* b1l = b1 + l * DIM;
        double* st1 = stats + (size_t)(l * 3 + 0) * 128;
        double* st2 = stats + (size_t)(l * 3 + 1) * 128;
        double* st3 = stats + (size_t)(l * 3 + 2) * 128;

        k_nodepq<<<2048, 256, 0, stream>>>(node, W1, l, P, Q, N);

        k_conv<0><<<2048, 256, 0, stream>>>(off, es, P, Q, Tl, b1l,
                                            nullptr, nullptr, nullptr,
                                            nullptr, nullptr, nullptr,
                                            st1, nullptr, N, invE);
        k_conv<2><<<2048, 256, 0, stream>>>(off, es, P, Q, Tl, b1l,
                                            st1, g1 + l * DIM, bt1 + l * DIM,
                                            nullptr, nullptr, nullptr,
                                            st2, nullptr, N, invE);
        k_conv<3><<<2048, 256, 0, stream>>>(off, es, P, Q, Tl, b1l,
                                            st1, g1 + l * DIM, bt1 + l * DIM,
                                            st2, g2 + l * DIM, bt2 + l * DIM,
                                            st3, agg, N, invE);

        k_nodeupd<<<(N * DIM + 255) / 256, 256, 0, stream>>>(node, agg, st3,
                                                             g3 + l * DIM, bt3 + l * DIM,
                                                             invN, N);
    }

    k_head<<<G, HID, 0, stream>>>(node, gid, N, Wfc, bfc, Wout, bout, (float*)d_out);
}

// Round 4
// 1071.648 us; speedup vs baseline: 2.2713x; 1.1312x over previous
//
#include <hip/hip_runtime.h>
#include <hip/hip_fp16.h>
#include <math.h>

#define DIM 64
#define NG 64
#define CIN 192
#define HID 128
#define NCONV 3
#define TB 8192
#define CUTOFF 12.0f
#define EPS 1e-5f
#define SCB 256

__device__ __forceinline__ float sp_(float y) {
    // softplus: max(y,0) + log(1 + exp(-|y|))
    return fmaxf(y, 0.f) + __logf(1.f + __expf(-fabsf(y)));
}
__device__ __forceinline__ float sig_(float y) {
    return 1.f / (1.f + __expf(-y));
}

// node[n][d] = embed_table[atom_types[n]][d]
__global__ void k_embed(const int* __restrict__ at, const float* __restrict__ emb,
                        float* __restrict__ node, int N) {
    int idx = blockIdx.x * blockDim.x + threadIdx.x;
    if (idx < N * DIM) {
        int n = idx >> 6, d = idx & 63;
        node[idx] = emb[at[n] * DIM + d];
    }
}

// T[l][i][d] = sum_g exp(coeff*(x_i-mu_g)^2) * W1[l][128+g][d]
__global__ void k_tables(const float* __restrict__ W1, float* __restrict__ T) {
    int row = blockIdx.x;            // 0 .. 3*TB-1
    int l = row / TB, i = row % TB;
    int d = threadIdx.x;             // 64 threads
    const float stepmu = CUTOFF / (float)(NG - 1);
    const float coeff = -0.5f / (stepmu * stepmu);
    float x = (float)i * (CUTOFF / (float)(TB - 1));
    __shared__ float rbf[NG];
    float mu = (float)d * stepmu;
    float diff = x - mu;
    rbf[d] = expf(coeff * diff * diff);
    __syncthreads();
    const float* w = W1 + (size_t)(l * CIN + 2 * DIM) * DIM;
    float acc = 0.f;
#pragma unroll 8
    for (int g = 0; g < NG; ++g) acc += rbf[g] * w[g * DIM + d];
    T[(size_t)row * DIM + d] = acc;
}

// ---- CSR build (dst-sorted edge permutation; dst fixed across layers) ----
__global__ void k_hist(const int* __restrict__ dst, int* __restrict__ cnt, int E) {
    for (int e = blockIdx.x * blockDim.x + threadIdx.x; e < E;
         e += gridDim.x * blockDim.x)
        atomicAdd(&cnt[dst[e]], 1);
}

__global__ void k_scanA(const int* __restrict__ cnt, int* __restrict__ bsum, int N) {
    __shared__ int lds[SCB];
    int i = blockIdx.x * SCB + threadIdx.x;
    lds[threadIdx.x] = (i < N) ? cnt[i] : 0;
    __syncthreads();
    for (int o = SCB / 2; o > 0; o >>= 1) {
        if (threadIdx.x < o) lds[threadIdx.x] += lds[threadIdx.x + o];
        __syncthreads();
    }
    if (threadIdx.x == 0) bsum[blockIdx.x] = lds[0];
}

__global__ void k_scanB(const int* __restrict__ bsum, int* __restrict__ bexcl, int NB) {
    __shared__ int lds[SCB];
    int t = threadIdx.x;
    int v = (t < NB) ? bsum[t] : 0;
    lds[t] = v;
    __syncthreads();
    for (int o = 1; o < SCB; o <<= 1) {
        int add = (t >= o) ? lds[t - o] : 0;
        __syncthreads();
        lds[t] += add;
        __syncthreads();
    }
    if (t < NB) bexcl[t] = lds[t] - v;   // exclusive
}

__global__ void k_scanC(const int* __restrict__ cnt, const int* __restrict__ bexcl,
                        int* __restrict__ off, int* __restrict__ cursor, int N, int E) {
    __shared__ int lds[SCB];
    int t = threadIdx.x;
    int i = blockIdx.x * SCB + t;
    int v = (i < N) ? cnt[i] : 0;
    lds[t] = v;
    __syncthreads();
    for (int o = 1; o < SCB; o <<= 1) {
        int add = (t >= o) ? lds[t - o] : 0;
        __syncthreads();
        lds[t] += add;
        __syncthreads();
    }
    if (i < N) {
        int excl = bexcl[blockIdx.x] + lds[t] - v;
        off[i] = excl;
        cursor[i] = excl;
        if (i == N - 1) off[N] = E;
    }
}

// scatter edges into dst-sorted order; pack (src, dist*inv_step) as int2
__global__ void k_scatter(const int* __restrict__ src, const int* __restrict__ dst,
                          const float* __restrict__ dist, int* __restrict__ cursor,
                          int2* __restrict__ es, int E) {
    const float inv_step = (float)(TB - 1) / CUTOFF;
    for (int e = blockIdx.x * blockDim.x + threadIdx.x; e < E;
         e += gridDim.x * blockDim.x) {
        int t = dst[e];
        int pos = atomicAdd(&cursor[t], 1);
        es[pos] = make_int2(src[e], __float_as_int(dist[e] * inv_step));
    }
}

// P = node @ W1[l][0:64], Q = node @ W1[l][64:128]
__global__ void k_nodepq(const float* __restrict__ node, const float* __restrict__ W1, int l,
                         float* __restrict__ P, float* __restrict__ Q, int N) {
    __shared__ float wa[DIM * DIM];
    __shared__ float wb[DIM * DIM];
    const float* WA = W1 + (size_t)(l * CIN) * DIM;
    for (int k = threadIdx.x; k < DIM * DIM; k += blockDim.x) {
        wa[k] = WA[k];
        wb[k] = WA[DIM * DIM + k];
    }
    __syncthreads();
    int lane = threadIdx.x & 63, w = threadIdx.x >> 6;
    int wpb = blockDim.x >> 6;
    for (int n = blockIdx.x * wpb + w; n < N; n += gridDim.x * wpb) {
        float nv = node[n * DIM + lane];
        float ap = 0.f, aq = 0.f;
#pragma unroll 8
        for (int k = 0; k < DIM; ++k) {
            float b = __shfl(nv, k);
            ap += b * wa[k * DIM + lane];
            aq += b * wb[k * DIM + lane];
        }
        P[n * DIM + lane] = ap;
        Q[n * DIM + lane] = aq;
    }
}

// ---------------- z16-cached plan (plan Z) ----------------
// Pass A: the ONLY random-gather pass per layer. z = P[src]+Q[dst]+R(x)+b1,
// stats(z), z16 = fp16(z).
__global__ void __launch_bounds__(256) k_convA(
        const int* __restrict__ off, const int2* __restrict__ es,
        const float* __restrict__ P, const float* __restrict__ Q,
        const float* __restrict__ T, const float* __restrict__ b1,
        double* __restrict__ stats, __half* __restrict__ z16, int N) {
    int lane = threadIdx.x & 63;
    int w = threadIdx.x >> 6;
    float bv = b1[lane];
    float s0 = 0.f, s1 = 0.f;
    int gw = blockIdx.x * 4 + w, nw = gridDim.x * 4;
    for (int n = gw; n < N; n += nw) {
        int e0 = off[n], e1 = off[n + 1];
        float qc = Q[n * DIM + lane] + bv;
        auto zed = [&](int2 ev) -> float {
            float u = __int_as_float(ev.y);
            int i = (int)u;
            i = max(0, min(i, TB - 2));
            float fr = u - (float)i;
            const float* t = T + i * DIM + lane;
            float t0 = t[0], t1 = t[DIM];
            return P[ev.x * DIM + lane] + t0 + fr * (t1 - t0) + qc;
        };
        int e = e0;
        for (; e + 4 <= e1; e += 4) {
            int2 eA = es[e], eB = es[e + 1], eC = es[e + 2], eD = es[e + 3];
            float zA = zed(eA), zB = zed(eB), zC = zed(eC), zD = zed(eD);
            z16[(size_t)e * DIM + lane] = __float2half(zA);
            z16[(size_t)(e + 1) * DIM + lane] = __float2half(zB);
            z16[(size_t)(e + 2) * DIM + lane] = __float2half(zC);
            z16[(size_t)(e + 3) * DIM + lane] = __float2half(zD);
            s0 += (zA + zB) + (zC + zD);
            s1 += (zA * zA + zB * zB) + (zC * zC + zD * zD);
        }
        for (; e < e1; ++e) {
            float z = zed(es[e]);
            z16[(size_t)e * DIM + lane] = __float2half(z);
            s0 += z; s1 += z * z;
        }
    }
    __shared__ float r0[4][64];
    __shared__ float r1[4][64];
    r0[w][lane] = s0;
    r1[w][lane] = s1;
    __syncthreads();
    if (threadIdx.x < 64) {
        int d = threadIdx.x;
        float t0 = r0[0][d] + r0[1][d] + r0[2][d] + r0[3][d];
        float t1 = r1[0][d] + r1[1][d] + r1[2][d] + r1[3][d];
        atomicAdd(&stats[d], (double)t0);
        atomicAdd(&stats[64 + d], (double)t1);
    }
}

// Pass B: flat streaming over z16; stats of f = sigmoid(bn1(z)).
// Thread handles 8 consecutive halves (dims (tid&7)*8 .. +7), uint4 load.
__global__ void __launch_bounds__(256) k_statsF(
        const __half* __restrict__ z16,
        const double* __restrict__ stA, const float* __restrict__ gA,
        const float* __restrict__ btA,
        double* __restrict__ stats, int total8, double invE) {
    int gq = threadIdx.x & 7;
    float a1[8], c1[8];
#pragma unroll
    for (int q = 0; q < 8; ++q) {
        int d = gq * 8 + q;
        double m = stA[d] * invE;
        double v = stA[64 + d] * invE - m * m;
        a1[q] = gA[d] / sqrtf((float)v + EPS);
        c1[q] = btA[d] - a1[q] * (float)m;
    }
    float s0[8] = {0, 0, 0, 0, 0, 0, 0, 0};
    float s1[8] = {0, 0, 0, 0, 0, 0, 0, 0};
    const uint4* z4 = (const uint4*)z16;
    int tid = blockIdx.x * blockDim.x + threadIdx.x;
    int stride = gridDim.x * blockDim.x;       // multiple of 8
    for (int i = tid; i < total8; i += stride) {
        uint4 v = z4[i];
        float2 p0 = __half22float2(*(const __half2*)&v.x);
        float2 p1 = __half22float2(*(const __half2*)&v.y);
        float2 p2 = __half22float2(*(const __half2*)&v.z);
        float2 p3 = __half22float2(*(const __half2*)&v.w);
        float f0 = sig_(a1[0] * p0.x + c1[0]);
        float f1 = sig_(a1[1] * p0.y + c1[1]);
        float f2 = sig_(a1[2] * p1.x + c1[2]);
        float f3 = sig_(a1[3] * p1.y + c1[3]);
        float f4 = sig_(a1[4] * p2.x + c1[4]);
        float f5 = sig_(a1[5] * p2.y + c1[5]);
        float f6 = sig_(a1[6] * p3.x + c1[6]);
        float f7 = sig_(a1[7] * p3.y + c1[7]);
        s0[0] += f0; s1[0] += f0 * f0;
        s0[1] += f1; s1[1] += f1 * f1;
        s0[2] += f2; s1[2] += f2 * f2;
        s0[3] += f3; s1[3] += f3 * f3;
        s0[4] += f4; s1[4] += f4 * f4;
        s0[5] += f5; s1[5] += f5 * f5;
        s0[6] += f6; s1[6] += f6 * f6;
        s0[7] += f7; s1[7] += f7 * f7;
    }
    __shared__ float lds[256][16];
#pragma unroll
    for (int q = 0; q < 8; ++q) {
        lds[threadIdx.x][q] = s0[q];
        lds[threadIdx.x][8 + q] = s1[q];
    }
    __syncthreads();
    if (threadIdx.x < 64) {
        int d = threadIdx.x;
        int grp = d >> 3, j = d & 7;
        float t0 = 0.f, t1 = 0.f;
        for (int k = 0; k < 32; ++k) {
            int t = k * 8 + grp;          // threads with (t&7)==grp
            t0 += lds[t][j];
            t1 += lds[t][8 + j];
        }
        atomicAdd(&stats[d], (double)t0);
        atomicAdd(&stats[64 + d], (double)t1);
    }
}

// Pass C: CSR streaming read of z16 (2 edges per wave: lanes 0-31 even edge,
// 32-63 odd edge; half2 = 2 dims per lane). h = f*softplus(bn2(f)),
// register segment-reduce -> agg[n] + node stats.
__global__ void __launch_bounds__(256) k_aggF(
        const int* __restrict__ off, const __half* __restrict__ z16,
        const double* __restrict__ stA, const float* __restrict__ gA,
        const float* __restrict__ btA,
        const double* __restrict__ stB, const float* __restrict__ gB,
        const float* __restrict__ btB,
        double* __restrict__ stats, float* __restrict__ agg, int N, double invE) {
    int lane = threadIdx.x & 63;
    int w = threadIdx.x >> 6;
    int j = lane & 31, c = lane >> 5;
    int d0 = 2 * j, d1 = d0 + 1;
    float a1x, c1x, a1y, c1y, a2x, c2x, a2y, c2y;
    {
        double m = stA[d0] * invE, v = stA[64 + d0] * invE - m * m;
        a1x = gA[d0] / sqrtf((float)v + EPS); c1x = btA[d0] - a1x * (float)m;
        m = stA[d1] * invE; v = stA[64 + d1] * invE - m * m;
        a1y = gA[d1] / sqrtf((float)v + EPS); c1y = btA[d1] - a1y * (float)m;
        m = stB[d0] * invE; v = stB[64 + d0] * invE - m * m;
        a2x = gB[d0] / sqrtf((float)v + EPS); c2x = btB[d0] - a2x * (float)m;
        m = stB[d1] * invE; v = stB[64 + d1] * invE - m * m;
        a2y = gB[d1] / sqrtf((float)v + EPS); c2y = btB[d1] - a2y * (float)m;
    }
    float s0x = 0.f, s1x = 0.f, s0y = 0.f, s1y = 0.f;
    int gw = blockIdx.x * 4 + w, nw = gridDim.x * 4;
    for (int n = gw; n < N; n += nw) {
        int e0 = off[n], e1 = off[n + 1];
        float ax = 0.f, ay = 0.f;
        int e = e0;
        for (; e + 2 <= e1; e += 2) {
            float2 z2 = __half22float2(*(const __half2*)&z16[(size_t)(e + c) * DIM + d0]);
            float fx = sig_(a1x * z2.x + c1x);
            float fy = sig_(a1y * z2.y + c1y);
            ax += fx * sp_(a2x * fx + c2x);
            ay += fy * sp_(a2y * fy + c2y);
        }
        if (e < e1 && c == 0) {
            float2 z2 = __half22float2(*(const __half2*)&z16[(size_t)e * DIM + d0]);
            float fx = sig_(a1x * z2.x + c1x);
            float fy = sig_(a1y * z2.y + c1y);
            ax += fx * sp_(a2x * fx + c2x);
            ay += fy * sp_(a2y * fy + c2y);
        }
        float ox = __shfl(ax, lane + 32);
        float oy = __shfl(ay, lane + 32);
        if (c == 0) {
            float tx = ax + ox, ty = ay + oy;
            float2 st; st.x = tx; st.y = ty;
            *(float2*)&agg[n * DIM + d0] = st;
            s0x += tx; s1x += tx * tx;
            s0y += ty; s1y += ty * ty;
        }
    }
    __shared__ float r0[4][64];
    __shared__ float r1[4][64];
    if (c == 0) {
        r0[w][d0] = s0x; r0[w][d1] = s0y;
        r1[w][d0] = s1x; r1[w][d1] = s1y;
    }
    __syncthreads();
    if (threadIdx.x < 64) {
        int d = threadIdx.x;
        float t0 = r0[0][d] + r0[1][d] + r0[2][d] + r0[3][d];
        float t1 = r1[0][d] + r1[1][d] + r1[2][d] + r1[3][d];
        atomicAdd(&stats[d], (double)t0);
        atomicAdd(&stats[64 + d], (double)t1);
    }
}

// ---------------- fallback (no z16 buffer): recompute passes ----------------
template <int MODE>
__global__ void __launch_bounds__(256) k_conv(
        const int* __restrict__ off, const int2* __restrict__ es,
        const float* __restrict__ P, const float* __restrict__ Q,
        const float* __restrict__ T, const float* __restrict__ b1,
        const double* __restrict__ stA, const float* __restrict__ gA,
        const float* __restrict__ btA,
        const double* __restrict__ stB, const float* __restrict__ gB,
        const float* __restrict__ btB,
        double* __restrict__ stats, float* __restrict__ agg, int N, double invE) {
    int lane = threadIdx.x & 63;
    int w = threadIdx.x >> 6;
    float bv = b1[lane];
    float a1 = 0.f, c1 = 0.f, a2 = 0.f, c2 = 0.f;
    if (MODE >= 2) {
        double m = stA[lane] * invE;
        double v = stA[64 + lane] * invE - m * m;
        a1 = gA[lane] / sqrtf((float)v + EPS);
        c1 = btA[lane] - a1 * (float)m;
    }
    if (MODE == 3) {
        double m = stB[lane] * invE;
        double v = stB[64 + lane] * invE - m * m;
        a2 = gB[lane] / sqrtf((float)v + EPS);
        c2 = btB[lane] - a2 * (float)m;
    }
    float s0 = 0.f, s1 = 0.f;
    int gw = blockIdx.x * 4 + w, nw = gridDim.x * 4;
    for (int n = gw; n < N; n += nw) {
        int e0 = off[n], e1 = off[n + 1];
        float qc = Q[n * DIM + lane] + bv;
        float acc = 0.f;
        auto body = [&](int2 ev) {
            float u = __int_as_float(ev.y);
            int i = (int)u;
            i = max(0, min(i, TB - 2));
            float fr = u - (float)i;
            const float* t = T + i * DIM + lane;
            float t0 = t[0], t1 = t[DIM];
            float z = P[ev.x * DIM + lane] + t0 + fr * (t1 - t0) + qc;
            if (MODE == 0) { s0 += z; s1 += z * z; }
            else {
                float f = sig_(a1 * z + c1);
                if (MODE == 2) { s0 += f; s1 += f * f; }
                else acc += f * sp_(a2 * f + c2);
            }
        };
        int e = e0;
        for (; e + 2 <= e1; e += 2) { body(es[e]); body(es[e + 1]); }
        if (e < e1) body(es[e]);
        if (MODE == 3) {
            agg[n * DIM + lane] = acc;
            s0 += acc; s1 += acc * acc;
        }
    }
    __shared__ float r0[4][64];
    __shared__ float r1[4][64];
    r0[w][lane] = s0;
    r1[w][lane] = s1;
    __syncthreads();
    if (threadIdx.x < 64) {
        int d = threadIdx.x;
        float t0 = r0[0][d] + r0[1][d] + r0[2][d] + r0[3][d];
        float t1 = r1[0][d] + r1[1][d] + r1[2][d] + r1[3][d];
        atomicAdd(&stats[d], (double)t0);
        atomicAdd(&stats[64 + d], (double)t1);
    }
}

// node += bn3(agg), coefficients computed inline from st3
__global__ void k_nodeupd(float* __restrict__ node, const float* __restrict__ agg,
                          const double* __restrict__ st, const float* __restrict__ g,
                          const float* __restrict__ bt, double invN, int N) {
    int idx = blockIdx.x * blockDim.x + threadIdx.x;
    if (idx < N * DIM) {
        int d = idx & 63;
        double m = st[d] * invN;
        double v = st[64 + d] * invN - m * m;
        float a = g[d] / sqrtf((float)v + EPS);
        float c = bt[d] - a * (float)m;
        node[idx] += a * agg[idx] + c;
    }
}

// per-graph mean pool (graph_ids sorted -> binary search) + softplus + MLP head
__global__ void k_head(const float* __restrict__ node, const int* __restrict__ gid, int N,
                       const float* __restrict__ Wfc, const float* __restrict__ bfc,
                       const float* __restrict__ Wout, const float* __restrict__ bout,
                       float* __restrict__ out) {
    int g = blockIdx.x;
    __shared__ int bounds[2];
    if (threadIdx.x == 0) {
        int lo = 0, hi = N;
        while (lo < hi) { int mid = (lo + hi) >> 1; if (gid[mid] < g) lo = mid + 1; else hi = mid; }
        bounds[0] = lo;
        int lo2 = lo; hi = N;
        while (lo2 < hi) { int mid = (lo2 + hi) >> 1; if (gid[mid] < g + 1) lo2 = mid + 1; else hi = mid; }
        bounds[1] = lo2;
    }
    __syncthreads();
    int s = bounds[0], e = bounds[1];
    __shared__ float sp[DIM];
    if (threadIdx.x < DIM) {
        float acc = 0.f;
        for (int n = s; n < e; ++n) acc += node[(size_t)n * DIM + threadIdx.x];
        float cntf = (float)max(e - s, 1);
        float m = acc / cntf;
        sp[threadIdx.x] = (m > 0.f) ? m + log1pf(expf(-m)) : log1pf(expf(m));
    }
    __syncthreads();
    int j = threadIdx.x;  // 128 threads
    float hj = bfc[j];
#pragma unroll 8
    for (int k = 0; k < DIM; ++k) hj += sp[k] * Wfc[k * HID + j];
    hj = (hj > 0.f) ? hj + log1pf(expf(-hj)) : log1pf(expf(hj));
    __shared__ float red[HID];
    red[j] = hj * Wout[j];
    __syncthreads();
    for (int o = HID / 2; o > 0; o >>= 1) {
        if (j < o) red[j] += red[j + o];
        __syncthreads();
    }
    if (j == 0) out[g] = red[0] + bout[0];
}

extern "C" void kernel_launch(void* const* d_in, const int* in_sizes, int n_in,
                              void* d_out, int out_size, void* d_ws, size_t ws_size,
                              hipStream_t stream) {
    const int* atom_types = (const int*)d_in[0];
    const int* src = (const int*)d_in[1];
    const int* dst = (const int*)d_in[2];
    const int* gid = (const int*)d_in[3];
    const float* dist = (const float*)d_in[4];
    const float* emb = (const float*)d_in[5];
    const float* W1 = (const float*)d_in[6];
    const float* b1 = (const float*)d_in[7];
    // d_in[8]=W2, d_in[9]=b2: dead (reference bug: fc_full2 output unused)
    const float* g1 = (const float*)d_in[10];
    const float* bt1 = (const float*)d_in[11];
    const float* g2 = (const float*)d_in[12];
    const float* bt2 = (const float*)d_in[13];
    const float* g3 = (const float*)d_in[14];
    const float* bt3 = (const float*)d_in[15];
    const float* Wfc = (const float*)d_in[16];
    const float* bfc = (const float*)d_in[17];
    const float* Wout = (const float*)d_in[18];
    const float* bout = (const float*)d_in[19];

    int N = in_sizes[0];
    int E = in_sizes[1];
    int G = out_size;
    int NB = (N + SCB - 1) / SCB;   // <= 256 for N <= 65536

    char* ws = (char*)d_ws;
    auto alloc = [&](size_t bytes) -> char* {
        char* p = ws;
        ws += (bytes + 255) & ~(size_t)255;
        return p;
    };
    size_t nd = (size_t)N * DIM * sizeof(float);
    float* node = (float*)alloc(nd);
    float* P = (float*)alloc(nd);
    float* Q = (float*)alloc(nd);
    float* agg = (float*)alloc(nd);
    float* T = (float*)alloc((size_t)NCONV * TB * DIM * sizeof(float));
    double* stats = (double*)alloc((size_t)NCONV * 3 * 128 * sizeof(double));
    int* off = (int*)alloc((size_t)(N + 1) * sizeof(int));
    int* cursor = (int*)alloc((size_t)N * sizeof(int));
    int* cnt = (int*)alloc((size_t)N * sizeof(int));
    int* bsum = (int*)alloc(SCB * sizeof(int));
    int* bexcl = (int*)alloc(SCB * sizeof(int));
    int2* es = (int2*)alloc((size_t)E * sizeof(int2));
    size_t zbytes = (size_t)E * DIM * sizeof(__half);
    size_t used = (size_t)(ws - (char*)d_ws);
    bool planZ = (used + zbytes) <= ws_size;
    __half* z16 = planZ ? (__half*)alloc(zbytes) : nullptr;

    hipMemsetAsync(stats, 0, (size_t)NCONV * 3 * 128 * sizeof(double), stream);
    hipMemsetAsync(cnt, 0, (size_t)N * sizeof(int), stream);

    k_embed<<<(N * DIM + 255) / 256, 256, 0, stream>>>(atom_types, emb, node, N);
    k_tables<<<NCONV * TB, 64, 0, stream>>>(W1, T);

    // CSR build (dst-sorted)
    k_hist<<<1024, 256, 0, stream>>>(dst, cnt, E);
    k_scanA<<<NB, SCB, 0, stream>>>(cnt, bsum, N);
    k_scanB<<<1, SCB, 0, stream>>>(bsum, bexcl, NB);
    k_scanC<<<NB, SCB, 0, stream>>>(cnt, bexcl, off, cursor, N, E);
    k_scatter<<<1024, 256, 0, stream>>>(src, dst, dist, cursor, es, E);

    double invE = 1.0 / (double)E;
    double invN = 1.0 / (double)N;

    for (int l = 0; l < NCONV; ++l) {
        const float* Tl = T + (size_t)l * TB * DIM;
        const float* b1l = b1 + l * DIM;
        double* st1 = stats + (size_t)(l * 3 + 0) * 128;
        double* st2 = stats + (size_t)(l * 3 + 1) * 128;
        double* st3 = stats + (size_t)(l * 3 + 2) * 128;

        k_nodepq<<<2048, 256, 0, stream>>>(node, W1, l, P, Q, N);

        if (planZ) {
            k_convA<<<2048, 256, 0, stream>>>(off, es, P, Q, Tl, b1l, st1, z16, N);
            k_statsF<<<2048, 256, 0, stream>>>(z16, st1, g1 + l * DIM, bt1 + l * DIM,
                                               st2, E * 8, invE);
            k_aggF<<<2048, 256, 0, stream>>>(off, z16,
                                             st1, g1 + l * DIM, bt1 + l * DIM,
                                             st2, g2 + l * DIM, bt2 + l * DIM,
                                             st3, agg, N, invE);
        } else {
            k_conv<0><<<2048, 256, 0, stream>>>(off, es, P, Q, Tl, b1l,
                                                nullptr, nullptr, nullptr,
                                                nullptr, nullptr, nullptr,
                                                st1, nullptr, N, invE);
            k_conv<2><<<2048, 256, 0, stream>>>(off, es, P, Q, Tl, b1l,
                                                st1, g1 + l * DIM, bt1 + l * DIM,
                                                nullptr, nullptr, nullptr,
                                                st2, nullptr, N, invE);
            k_conv<3><<<2048, 256, 0, stream>>>(off, es, P, Q, Tl, b1l,
                                                st1, g1 + l * DIM, bt1 + l * DIM,
                                                st2, g2 + l * DIM, bt2 + l * DIM,
                                                st3, agg, N, invE);
        }

        k_nodeupd<<<(N * DIM + 255) / 256, 256, 0, stream>>>(node, agg, st3,
                                                             g3 + l * DIM, bt3 + l * DIM,
                                                             invN, N);
    }

    k_head<<<G, HID, 0, stream>>>(node, gid, N, Wfc, bfc, Wout, bout, (float*)d_out);
}

// Round 5
// 1054.324 us; speedup vs baseline: 2.3086x; 1.0164x over previous
//
#include <hip/hip_runtime.h>
#include <hip/hip_fp16.h>
#include <math.h>

#define DIM 64
#define NG 64
#define CIN 192
#define HID 128
#define NCONV 3
#define TB 8192
#define CUTOFF 12.0f
#define EPS 1e-5f
#define SCB 256

typedef int i4v __attribute__((ext_vector_type(4)));

__device__ __forceinline__ float sp_(float y) {
    return fmaxf(y, 0.f) + __logf(1.f + __expf(-fabsf(y)));
}
__device__ __forceinline__ float sig_(float y) {
    return 1.f / (1.f + __expf(-y));
}
__device__ __forceinline__ void st_nt_h(__half* p, float v) {
    __half h = __float2half(v);
    unsigned short u;
    __builtin_memcpy(&u, &h, 2);
    __builtin_nontemporal_store(u, (unsigned short*)p);
}
__device__ __forceinline__ float2 h2f2_bits(int bits) {
    __half2 h;
    __builtin_memcpy(&h, &bits, 4);
    return __half22float2(h);
}

// Tp[l][i][d] = half2( R_l(x_i)[d], R_l(x_{i+1})[d] )
__global__ void k_tables(const float* __restrict__ W1, __half2* __restrict__ Tp) {
    int row = blockIdx.x;            // 0 .. 3*TB-1
    int l = row / TB, i = row % TB;
    int d = threadIdx.x;             // 64 threads
    const float stepmu = CUTOFF / (float)(NG - 1);
    const float coeff = -0.5f / (stepmu * stepmu);
    const float stepx = CUTOFF / (float)(TB - 1);
    float x0 = (float)i * stepx;
    float x1 = fminf((float)(i + 1), (float)(TB - 1)) * stepx;
    __shared__ float r0[NG];
    __shared__ float r1[NG];
    float mu = (float)d * stepmu;
    float d0 = x0 - mu, d1 = x1 - mu;
    r0[d] = expf(coeff * d0 * d0);
    r1[d] = expf(coeff * d1 * d1);
    __syncthreads();
    const float* w = W1 + (size_t)(l * CIN + 2 * DIM) * DIM;
    float a0 = 0.f, a1 = 0.f;
#pragma unroll 8
    for (int g = 0; g < NG; ++g) {
        float wv = w[g * DIM + d];
        a0 += r0[g] * wv;
        a1 += r1[g] * wv;
    }
    __half2 hh;
    hh.x = __float2half(a0);
    hh.y = __float2half(a1);
    Tp[(size_t)row * DIM + d] = hh;
}

// ---- CSR build (dst-sorted edge permutation; dst fixed across layers) ----
__global__ void k_hist(const int* __restrict__ dst, int* __restrict__ cnt, int E) {
    for (int e = blockIdx.x * blockDim.x + threadIdx.x; e < E;
         e += gridDim.x * blockDim.x)
        atomicAdd(&cnt[dst[e]], 1);
}

__global__ void k_scanA(const int* __restrict__ cnt, int* __restrict__ bsum, int N) {
    __shared__ int lds[SCB];
    int i = blockIdx.x * SCB + threadIdx.x;
    lds[threadIdx.x] = (i < N) ? cnt[i] : 0;
    __syncthreads();
    for (int o = SCB / 2; o > 0; o >>= 1) {
        if (threadIdx.x < o) lds[threadIdx.x] += lds[threadIdx.x + o];
        __syncthreads();
    }
    if (threadIdx.x == 0) bsum[blockIdx.x] = lds[0];
}

__global__ void k_scanB(const int* __restrict__ bsum, int* __restrict__ bexcl, int NB) {
    __shared__ int lds[SCB];
    int t = threadIdx.x;
    int v = (t < NB) ? bsum[t] : 0;
    lds[t] = v;
    __syncthreads();
    for (int o = 1; o < SCB; o <<= 1) {
        int add = (t >= o) ? lds[t - o] : 0;
        __syncthreads();
        lds[t] += add;
        __syncthreads();
    }
    if (t < NB) bexcl[t] = lds[t] - v;   // exclusive
}

__global__ void k_scanC(const int* __restrict__ cnt, const int* __restrict__ bexcl,
                        int* __restrict__ off, int* __restrict__ cursor, int N, int E) {
    __shared__ int lds[SCB];
    int t = threadIdx.x;
    int i = blockIdx.x * SCB + t;
    int v = (i < N) ? cnt[i] : 0;
    lds[t] = v;
    __syncthreads();
    for (int o = 1; o < SCB; o <<= 1) {
        int add = (t >= o) ? lds[t - o] : 0;
        __syncthreads();
        lds[t] += add;
        __syncthreads();
    }
    if (i < N) {
        int excl = bexcl[blockIdx.x] + lds[t] - v;
        off[i] = excl;
        cursor[i] = excl;
        if (i == N - 1) off[N] = E;
    }
}

// scatter edges into dst-sorted order; pack (src, dist*inv_step) as int2
__global__ void k_scatter(const int* __restrict__ src, const int* __restrict__ dst,
                          const float* __restrict__ dist, int* __restrict__ cursor,
                          int2* __restrict__ es, int E) {
    const float inv_step = (float)(TB - 1) / CUTOFF;
    for (int e = blockIdx.x * blockDim.x + threadIdx.x; e < E;
         e += gridDim.x * blockDim.x) {
        int t = dst[e];
        int pos = atomicAdd(&cursor[t], 1);
        es[pos] = make_int2(src[e], __float_as_int(dist[e] * inv_step));
    }
}

// Fused node-state + P/Q kernel.
// FIRST=1: node = embed_table[atom_types].  FIRST=0: node += bn3(agg) inline.
// Then P16 = half(node @ W1a), Q = node @ W1b.
template <int FIRST>
__global__ void __launch_bounds__(256) k_pq(
        const int* __restrict__ at, const float* __restrict__ emb,
        float* __restrict__ node, const float* __restrict__ agg,
        const double* __restrict__ st, const float* __restrict__ g3,
        const float* __restrict__ bt3, double invN,
        const float* __restrict__ W1, int l,
        __half* __restrict__ P16, float* __restrict__ Q, int N) {
    __shared__ float wa[DIM * DIM];
    __shared__ float wb[DIM * DIM];
    const float* WA = W1 + (size_t)(l * CIN) * DIM;
    for (int k = threadIdx.x; k < DIM * DIM; k += blockDim.x) {
        wa[k] = WA[k];
        wb[k] = WA[DIM * DIM + k];
    }
    int lane = threadIdx.x & 63, w = threadIdx.x >> 6;
    float a3 = 0.f, c3 = 0.f;
    if (!FIRST) {
        double m = st[lane] * invN;
        double v = st[64 + lane] * invN - m * m;
        a3 = g3[lane] / sqrtf((float)v + EPS);
        c3 = bt3[lane] - a3 * (float)m;
    }
    __syncthreads();
    int wpb = blockDim.x >> 6;
    for (int n = blockIdx.x * wpb + w; n < N; n += gridDim.x * wpb) {
        float nv;
        if (FIRST) {
            nv = emb[at[n] * DIM + lane];
        } else {
            nv = node[n * DIM + lane] + a3 * agg[n * DIM + lane] + c3;
        }
        node[n * DIM + lane] = nv;
        float ap = 0.f, aq = 0.f;
#pragma unroll 8
        for (int k = 0; k < DIM; ++k) {
            float b = __shfl(nv, k);
            ap += b * wa[k * DIM + lane];
            aq += b * wb[k * DIM + lane];
        }
        P16[n * DIM + lane] = __float2half(ap);
        Q[n * DIM + lane] = aq;
    }
}

// Pass A: the ONLY random-gather pass per layer. z = P[src]+Q[dst]+R(x)+b1,
// stats(z), z16 = fp16(z) (nontemporal store).
__global__ void __launch_bounds__(256) k_convA(
        const int* __restrict__ off, const int2* __restrict__ es,
        const __half* __restrict__ P16, const float* __restrict__ Q,
        const __half2* __restrict__ Tp, const float* __restrict__ b1,
        double* __restrict__ stats, __half* __restrict__ z16, int N) {
    int lane = threadIdx.x & 63;
    int w = threadIdx.x >> 6;
    float bv = b1[lane];
    float s0 = 0.f, s1 = 0.f;
    int gw = blockIdx.x * 4 + w, nw = gridDim.x * 4;
    for (int n = gw; n < N; n += nw) {
        int e0 = off[n], e1 = off[n + 1];
        float qc = Q[n * DIM + lane] + bv;
        auto zed = [&](int2 ev) -> float {
            float u = __int_as_float(ev.y);
            int i = (int)u;
            i = max(0, min(i, TB - 2));
            float fr = u - (float)i;
            float2 t2 = __half22float2(Tp[(size_t)i * DIM + lane]);
            float p = __half2float(P16[(size_t)ev.x * DIM + lane]);
            return p + t2.x + fr * (t2.y - t2.x) + qc;
        };
        int e = e0;
        for (; e + 4 <= e1; e += 4) {
            int2 eA = es[e], eB = es[e + 1], eC = es[e + 2], eD = es[e + 3];
            float zA = zed(eA), zB = zed(eB), zC = zed(eC), zD = zed(eD);
            st_nt_h(z16 + ((size_t)e) * DIM + lane, zA);
            st_nt_h(z16 + ((size_t)(e + 1)) * DIM + lane, zB);
            st_nt_h(z16 + ((size_t)(e + 2)) * DIM + lane, zC);
            st_nt_h(z16 + ((size_t)(e + 3)) * DIM + lane, zD);
            s0 += (zA + zB) + (zC + zD);
            s1 += (zA * zA + zB * zB) + (zC * zC + zD * zD);
        }
        for (; e < e1; ++e) {
            float z = zed(es[e]);
            st_nt_h(z16 + ((size_t)e) * DIM + lane, z);
            s0 += z; s1 += z * z;
        }
    }
    __shared__ float r0[4][64];
    __shared__ float r1[4][64];
    r0[w][lane] = s0;
    r1[w][lane] = s1;
    __syncthreads();
    if (threadIdx.x < 64) {
        int d = threadIdx.x;
        float t0 = r0[0][d] + r0[1][d] + r0[2][d] + r0[3][d];
        float t1 = r1[0][d] + r1[1][d] + r1[2][d] + r1[3][d];
        atomicAdd(&stats[d], (double)t0);
        atomicAdd(&stats[64 + d], (double)t1);
    }
}

// Pass B: flat streaming over z16 (nontemporal uint4); stats of sigmoid(bn1(z)).
__global__ void __launch_bounds__(256) k_statsF(
        const __half* __restrict__ z16,
        const double* __restrict__ stA, const float* __restrict__ gA,
        const float* __restrict__ btA,
        double* __restrict__ stats, int total8, double invE) {
    int gq = threadIdx.x & 7;
    float a1[8], c1[8];
#pragma unroll
    for (int q = 0; q < 8; ++q) {
        int d = gq * 8 + q;
        double m = stA[d] * invE;
        double v = stA[64 + d] * invE - m * m;
        a1[q] = gA[d] / sqrtf((float)v + EPS);
        c1[q] = btA[d] - a1[q] * (float)m;
    }
    float s0[8] = {0, 0, 0, 0, 0, 0, 0, 0};
    float s1[8] = {0, 0, 0, 0, 0, 0, 0, 0};
    const i4v* z4 = (const i4v*)z16;
    int tid = blockIdx.x * blockDim.x + threadIdx.x;
    int stride = gridDim.x * blockDim.x;       // multiple of 8
    for (int i = tid; i < total8; i += stride) {
        i4v v = __builtin_nontemporal_load(z4 + i);
        float2 p0 = h2f2_bits(v.x);
        float2 p1 = h2f2_bits(v.y);
        float2 p2 = h2f2_bits(v.z);
        float2 p3 = h2f2_bits(v.w);
        float f0 = sig_(a1[0] * p0.x + c1[0]);
        float f1 = sig_(a1[1] * p0.y + c1[1]);
        float f2 = sig_(a1[2] * p1.x + c1[2]);
        float f3 = sig_(a1[3] * p1.y + c1[3]);
        float f4 = sig_(a1[4] * p2.x + c1[4]);
        float f5 = sig_(a1[5] * p2.y + c1[5]);
        float f6 = sig_(a1[6] * p3.x + c1[6]);
        float f7 = sig_(a1[7] * p3.y + c1[7]);
        s0[0] += f0; s1[0] += f0 * f0;
        s0[1] += f1; s1[1] += f1 * f1;
        s0[2] += f2; s1[2] += f2 * f2;
        s0[3] += f3; s1[3] += f3 * f3;
        s0[4] += f4; s1[4] += f4 * f4;
        s0[5] += f5; s1[5] += f5 * f5;
        s0[6] += f6; s1[6] += f6 * f6;
        s0[7] += f7; s1[7] += f7 * f7;
    }
    __shared__ float lds[256][16];
#pragma unroll
    for (int q = 0; q < 8; ++q) {
        lds[threadIdx.x][q] = s0[q];
        lds[threadIdx.x][8 + q] = s1[q];
    }
    __syncthreads();
    if (threadIdx.x < 64) {
        int d = threadIdx.x;
        int grp = d >> 3, j = d & 7;
        float t0 = 0.f, t1 = 0.f;
        for (int k = 0; k < 32; ++k) {
            int t = k * 8 + grp;          // threads with (t&7)==grp
            t0 += lds[t][j];
            t1 += lds[t][8 + j];
        }
        atomicAdd(&stats[d], (double)t0);
        atomicAdd(&stats[64 + d], (double)t1);
    }
}

// Pass C: CSR streaming read of z16 (2 edges/wave, half2/lane, nontemporal).
// h = f*softplus(bn2(f)), register segment-reduce -> agg[n] + node stats.
__global__ void __launch_bounds__(256) k_aggF(
        const int* __restrict__ off, const __half* __restrict__ z16,
        const double* __restrict__ stA, const float* __restrict__ gA,
        const float* __restrict__ btA,
        const double* __restrict__ stB, const float* __restrict__ gB,
        const float* __restrict__ btB,
        double* __restrict__ stats, float* __restrict__ agg, int N, double invE) {
    int lane = threadIdx.x & 63;
    int w = threadIdx.x >> 6;
    int j = lane & 31, c = lane >> 5;
    int d0 = 2 * j, d1 = d0 + 1;
    float a1x, c1x, a1y, c1y, a2x, c2x, a2y, c2y;
    {
        double m = stA[d0] * invE, v = stA[64 + d0] * invE - m * m;
        a1x = gA[d0] / sqrtf((float)v + EPS); c1x = btA[d0] - a1x * (float)m;
        m = stA[d1] * invE; v = stA[64 + d1] * invE - m * m;
        a1y = gA[d1] / sqrtf((float)v + EPS); c1y = btA[d1] - a1y * (float)m;
        m = stB[d0] * invE; v = stB[64 + d0] * invE - m * m;
        a2x = gB[d0] / sqrtf((float)v + EPS); c2x = btB[d0] - a2x * (float)m;
        m = stB[d1] * invE; v = stB[64 + d1] * invE - m * m;
        a2y = gB[d1] / sqrtf((float)v + EPS); c2y = btB[d1] - a2y * (float)m;
    }
    float s0x = 0.f, s1x = 0.f, s0y = 0.f, s1y = 0.f;
    int gw = blockIdx.x * 4 + w, nw = gridDim.x * 4;
    for (int n = gw; n < N; n += nw) {
        int e0 = off[n], e1 = off[n + 1];
        float ax = 0.f, ay = 0.f;
        int e = e0;
        for (; e + 2 <= e1; e += 2) {
            int bits = __builtin_nontemporal_load(
                (const int*)(z16 + ((size_t)(e + c)) * DIM + d0));
            float2 z2 = h2f2_bits(bits);
            float fx = sig_(a1x * z2.x + c1x);
            float fy = sig_(a1y * z2.y + c1y);
            ax += fx * sp_(a2x * fx + c2x);
            ay += fy * sp_(a2y * fy + c2y);
        }
        if (e < e1 && c == 0) {
            int bits = __builtin_nontemporal_load(
                (const int*)(z16 + ((size_t)e) * DIM + d0));
            float2 z2 = h2f2_bits(bits);
            float fx = sig_(a1x * z2.x + c1x);
            float fy = sig_(a1y * z2.y + c1y);
            ax += fx * sp_(a2x * fx + c2x);
            ay += fy * sp_(a2y * fy + c2y);
        }
        float ox = __shfl(ax, lane + 32);
        float oy = __shfl(ay, lane + 32);
        if (c == 0) {
            float tx = ax + ox, ty = ay + oy;
            float2 st; st.x = tx; st.y = ty;
            *(float2*)&agg[n * DIM + d0] = st;
            s0x += tx; s1x += tx * tx;
            s0y += ty; s1y += ty * ty;
        }
    }
    __shared__ float r0[4][64];
    __shared__ float r1[4][64];
    if (c == 0) {
        r0[w][d0] = s0x; r0[w][d1] = s0y;
        r1[w][d0] = s1x; r1[w][d1] = s1y;
    }
    __syncthreads();
    if (threadIdx.x < 64) {
        int d = threadIdx.x;
        float t0 = r0[0][d] + r0[1][d] + r0[2][d] + r0[3][d];
        float t1 = r1[0][d] + r1[1][d] + r1[2][d] + r1[3][d];
        atomicAdd(&stats[d], (double)t0);
        atomicAdd(&stats[64 + d], (double)t1);
    }
}

// ---------------- fallback (no z16 buffer): recompute passes ----------------
template <int MODE>
__global__ void __launch_bounds__(256) k_conv(
        const int* __restrict__ off, const int2* __restrict__ es,
        const __half* __restrict__ P16, const float* __restrict__ Q,
        const __half2* __restrict__ Tp, const float* __restrict__ b1,
        const double* __restrict__ stA, const float* __restrict__ gA,
        const float* __restrict__ btA,
        const double* __restrict__ stB, const float* __restrict__ gB,
        const float* __restrict__ btB,
        double* __restrict__ stats, float* __restrict__ agg, int N, double invE) {
    int lane = threadIdx.x & 63;
    int w = threadIdx.x >> 6;
    float bv = b1[lane];
    float a1 = 0.f, c1 = 0.f, a2 = 0.f, c2 = 0.f;
    if (MODE >= 2) {
        double m = stA[lane] * invE;
        double v = stA[64 + lane] * invE - m * m;
        a1 = gA[lane] / sqrtf((float)v + EPS);
        c1 = btA[lane] - a1 * (float)m;
    }
    if (MODE == 3) {
        double m = stB[lane] * invE;
        double v = stB[64 + lane] * invE - m * m;
        a2 = gB[lane] / sqrtf((float)v + EPS);
        c2 = btB[lane] - a2 * (float)m;
    }
    float s0 = 0.f, s1 = 0.f;
    int gw = blockIdx.x * 4 + w, nw = gridDim.x * 4;
    for (int n = gw; n < N; n += nw) {
        int e0 = off[n], e1 = off[n + 1];
        float qc = Q[n * DIM + lane] + bv;
        float acc = 0.f;
        auto body = [&](int2 ev) {
            float u = __int_as_float(ev.y);
            int i = (int)u;
            i = max(0, min(i, TB - 2));
            float fr = u - (float)i;
            float2 t2 = __half22float2(Tp[(size_t)i * DIM + lane]);
            float p = __half2float(P16[(size_t)ev.x * DIM + lane]);
            float z = p + t2.x + fr * (t2.y - t2.x) + qc;
            if (MODE == 0) { s0 += z; s1 += z * z; }
            else {
                float f = sig_(a1 * z + c1);
                if (MODE == 2) { s0 += f; s1 += f * f; }
                else acc += f * sp_(a2 * f + c2);
            }
        };
        int e = e0;
        for (; e + 2 <= e1; e += 2) { body(es[e]); body(es[e + 1]); }
        if (e < e1) body(es[e]);
        if (MODE == 3) {
            agg[n * DIM + lane] = acc;
            s0 += acc; s1 += acc * acc;
        }
    }
    __shared__ float r0[4][64];
    __shared__ float r1[4][64];
    r0[w][lane] = s0;
    r1[w][lane] = s1;
    __syncthreads();
    if (threadIdx.x < 64) {
        int d = threadIdx.x;
        float t0 = r0[0][d] + r0[1][d] + r0[2][d] + r0[3][d];
        float t1 = r1[0][d] + r1[1][d] + r1[2][d] + r1[3][d];
        atomicAdd(&stats[d], (double)t0);
        atomicAdd(&stats[64 + d], (double)t1);
    }
}

// per-graph mean pool of bn3-updated node (bn3 folded in) + softplus + MLP head
__global__ void k_head(const float* __restrict__ node, const float* __restrict__ agg,
                       const double* __restrict__ st, const float* __restrict__ g3,
                       const float* __restrict__ bt3, double invN,
                       const int* __restrict__ gid, int N,
                       const float* __restrict__ Wfc, const float* __restrict__ bfc,
                       const float* __restrict__ Wout, const float* __restrict__ bout,
                       float* __restrict__ out) {
    int g = blockIdx.x;
    __shared__ int bounds[2];
    if (threadIdx.x == 0) {
        int lo = 0, hi = N;
        while (lo < hi) { int mid = (lo + hi) >> 1; if (gid[mid] < g) lo = mid + 1; else hi = mid; }
        bounds[0] = lo;
        int lo2 = lo; hi = N;
        while (lo2 < hi) { int mid = (lo2 + hi) >> 1; if (gid[mid] < g + 1) lo2 = mid + 1; else hi = mid; }
        bounds[1] = lo2;
    }
    __syncthreads();
    int s = bounds[0], e = bounds[1];
    __shared__ float sp[DIM];
    if (threadIdx.x < DIM) {
        int d = threadIdx.x;
        double mm = st[d] * invN;
        double vv = st[64 + d] * invN - mm * mm;
        float a3 = g3[d] / sqrtf((float)vv + EPS);
        float c3 = bt3[d] - a3 * (float)mm;
        float sn = 0.f, sa = 0.f;
        for (int n = s; n < e; ++n) {
            sn += node[(size_t)n * DIM + d];
            sa += agg[(size_t)n * DIM + d];
        }
        float cntf = (float)max(e - s, 1);
        float m = (sn + a3 * sa) / cntf + c3;
        sp[d] = (m > 0.f) ? m + log1pf(expf(-m)) : log1pf(expf(m));
    }
    __syncthreads();
    int j = threadIdx.x;  // 128 threads
    float hj = bfc[j];
#pragma unroll 8
    for (int k = 0; k < DIM; ++k) hj += sp[k] * Wfc[k * HID + j];
    hj = (hj > 0.f) ? hj + log1pf(expf(-hj)) : log1pf(expf(hj));
    __shared__ float red[HID];
    red[j] = hj * Wout[j];
    __syncthreads();
    for (int o = HID / 2; o > 0; o >>= 1) {
        if (j < o) red[j] += red[j + o];
        __syncthreads();
    }
    if (j == 0) out[g] = red[0] + bout[0];
}

extern "C" void kernel_launch(void* const* d_in, const int* in_sizes, int n_in,
                              void* d_out, int out_size, void* d_ws, size_t ws_size,
                              hipStream_t stream) {
    const int* atom_types = (const int*)d_in[0];
    const int* src = (const int*)d_in[1];
    const int* dst = (const int*)d_in[2];
    const int* gid = (const int*)d_in[3];
    const float* dist = (const float*)d_in[4];
    const float* emb = (const float*)d_in[5];
    const float* W1 = (const float*)d_in[6];
    const float* b1 = (const float*)d_in[7];
    // d_in[8]=W2, d_in[9]=b2: dead (reference bug: fc_full2 output unused)
    const float* g1 = (const float*)d_in[10];
    const float* bt1 = (const float*)d_in[11];
    const float* g2 = (const float*)d_in[12];
    const float* bt2 = (const float*)d_in[13];
    const float* g3 = (const float*)d_in[14];
    const float* bt3 = (const float*)d_in[15];
    const float* Wfc = (const float*)d_in[16];
    const float* bfc = (const float*)d_in[17];
    const float* Wout = (const float*)d_in[18];
    const float* bout = (const float*)d_in[19];

    int N = in_sizes[0];
    int E = in_sizes[1];
    int G = out_size;
    int NB = (N + SCB - 1) / SCB;   // <= 256 for N <= 65536

    char* ws = (char*)d_ws;
    auto alloc = [&](size_t bytes) -> char* {
        char* p = ws;
        ws += (bytes + 255) & ~(size_t)255;
        return p;
    };
    size_t nd = (size_t)N * DIM * sizeof(float);
    float* node = (float*)alloc(nd);
    __half* P16 = (__half*)alloc(nd / 2);
    float* Q = (float*)alloc(nd);
    float* agg = (float*)alloc(nd);
    __half2* Tp = (__half2*)alloc((size_t)NCONV * TB * DIM * sizeof(__half2));
    double* stats = (double*)alloc((size_t)NCONV * 3 * 128 * sizeof(double));
    int* off = (int*)alloc((size_t)(N + 1) * sizeof(int));
    int* cursor = (int*)alloc((size_t)N * sizeof(int));
    int* cnt = (int*)alloc((size_t)N * sizeof(int));
    int* bsum = (int*)alloc(SCB * sizeof(int));
    int* bexcl = (int*)alloc(SCB * sizeof(int));
    int2* es = (int2*)alloc((size_t)E * sizeof(int2));
    size_t zbytes = (size_t)E * DIM * sizeof(__half);
    size_t used = (size_t)(ws - (char*)d_ws);
    bool planZ = (used + zbytes) <= ws_size;
    __half* z16 = planZ ? (__half*)alloc(zbytes) : nullptr;

    hipMemsetAsync(stats, 0, (size_t)NCONV * 3 * 128 * sizeof(double), stream);
    hipMemsetAsync(cnt, 0, (size_t)N * sizeof(int), stream);

    k_tables<<<NCONV * TB, 64, 0, stream>>>(W1, Tp);

    // CSR build (dst-sorted)
    k_hist<<<1024, 256, 0, stream>>>(dst, cnt, E);
    k_scanA<<<NB, SCB, 0, stream>>>(cnt, bsum, N);
    k_scanB<<<1, SCB, 0, stream>>>(bsum, bexcl, NB);
    k_scanC<<<NB, SCB, 0, stream>>>(cnt, bexcl, off, cursor, N, E);
    k_scatter<<<1024, 256, 0, stream>>>(src, dst, dist, cursor, es, E);

    double invE = 1.0 / (double)E;
    double invN = 1.0 / (double)N;

    for (int l = 0; l < NCONV; ++l) {
        const __half2* Tl = Tp + (size_t)l * TB * DIM;
        const float* b1l = b1 + l * DIM;
        double* st1 = stats + (size_t)(l * 3 + 0) * 128;
        double* st2 = stats + (size_t)(l * 3 + 1) * 128;
        double* st3 = stats + (size_t)(l * 3 + 2) * 128;

        if (l == 0) {
            k_pq<1><<<2048, 256, 0, stream>>>(atom_types, emb, node, nullptr,
                                              nullptr, nullptr, nullptr, 0.0,
                                              W1, l, P16, Q, N);
        } else {
            double* st3p = stats + (size_t)((l - 1) * 3 + 2) * 128;
            k_pq<0><<<2048, 256, 0, stream>>>(atom_types, emb, node, agg,
                                              st3p, g3 + (l - 1) * DIM,
                                              bt3 + (l - 1) * DIM, invN,
                                              W1, l, P16, Q, N);
        }

        if (planZ) {
            k_convA<<<2048, 256, 0, stream>>>(off, es, P16, Q, Tl, b1l, st1, z16, N);
            k_statsF<<<2048, 256, 0, stream>>>(z16, st1, g1 + l * DIM, bt1 + l * DIM,
                                               st2, E * 8, invE);
            k_aggF<<<2048, 256, 0, stream>>>(off, z16,
                                             st1, g1 + l * DIM, bt1 + l * DIM,
                                             st2, g2 + l * DIM, bt2 + l * DIM,
                                             st3, agg, N, invE);
        } else {
            k_conv<0><<<2048, 256, 0, stream>>>(off, es, P16, Q, Tl, b1l,
                                                nullptr, nullptr, nullptr,
                                                nullptr, nullptr, nullptr,
                                                st1, nullptr, N, invE);
            k_conv<2><<<2048, 256, 0, stream>>>(off, es, P16, Q, Tl, b1l,
                                                st1, g1 + l * DIM, bt1 + l * DIM,
                                                nullptr, nullptr, nullptr,
                                                st2, nullptr, N, invE);
            k_conv<3><<<2048, 256, 0, stream>>>(off, es, P16, Q, Tl, b1l,
                                                st1, g1 + l * DIM, bt1 + l * DIM,
                                                st2, g2 + l * DIM, bt2 + l * DIM,
                                                st3, agg, N, invE);
        }
    }

    double* st3f = stats + (size_t)(2 * 3 + 2) * 128;
    k_head<<<G, HID, 0, stream>>>(node, agg, st3f, g3 + 2 * DIM, bt3 + 2 * DIM,
                                  invN, gid, N, Wfc, bfc, Wout, bout, (float*)d_out);
}